// Round 19
// baseline (1604.179 us; speedup 1.0000x reference)
//
#include <hip/hip_runtime.h>
#include <stdint.h>

#define NN 100000
#define NE 600000
#define NG 64
#define HD 128
#define HD2 (HD*HD)
#define NLAYER 4
#define SCAN_NB 391   // ceil(NN/256)
#define NTILES ((NN + 63) / 64)
#define PSLICE 16

typedef unsigned short u16;
typedef unsigned int u32;
typedef unsigned long long u64;
typedef __attribute__((ext_vector_type(8))) short bf16x8;   // 8 bf16 = 4 VGPR
typedef __attribute__((ext_vector_type(4))) float f32x4;

__device__ __forceinline__ float bf2f(u32 v) { return __uint_as_float(v << 16); }
__device__ __forceinline__ u16 f2bf(float f) {
    u32 u = __float_as_uint(f);
    return (u16)((u + 0x7FFFu + ((u >> 16) & 1u)) >> 16);
}
__device__ __forceinline__ u32 pk2(float a, float b) {
    return (u32)f2bf(a) | ((u32)f2bf(b) << 16);
}

// ---------------------------------------------------------------------------
// MFMA GEMM (measured good - unchanged, grid 512).
// ---------------------------------------------------------------------------
template<bool RELU, bool GATE>
__global__ __launch_bounds__(256, 3) void mgemm_kernel(
    const u16* __restrict__ Xb, const u16* __restrict__ Wt,
    const float* __restrict__ bias, const float* __restrict__ degscale,
    const u16* __restrict__ addend, u16* __restrict__ out, int M,
    const float* __restrict__ gw2, const float* __restrict__ gb2,
    float* __restrict__ gate)
{
    __shared__ u16 WsL[HD * HD];   // 32 KB swizzled weights
    __shared__ u16 XsL[64 * HD];   // 16 KB swizzled X tile
    const int t = threadIdx.x;
    const int lane = t & 63, wave = t >> 6;
    const int cj = ((lane >> 4) << 2);

    for (int i = t; i < HD * 16; i += 256) {
        const int row = i >> 4, c16 = i & 15;
        uint4 v = *(const uint4*)(Wt + (size_t)row * HD + c16 * 8);
        *(uint4*)((char*)WsL + (((row << 8) + (c16 << 4)) ^ ((row & 7) << 4))) = v;
    }
    float4 bcol[8];
    #pragma unroll
    for (int ct = 0; ct < 8; ct++)
        bcol[ct] = bias ? *(const float4*)(bias + ct * 16 + cj)
                        : make_float4(0.f, 0.f, 0.f, 0.f);
    float4 gwv[8];
    if (GATE) {
        #pragma unroll
        for (int ct = 0; ct < 8; ct++)
            gwv[ct] = *(const float4*)(gw2 + ct * 16 + cj);
    }

    const int arow = wave * 16 + (lane & 15);
    const int alin = (arow << 8) + ((lane >> 4) << 4);
    const int axor = (arow & 7) << 4;
    __syncthreads();

    for (int tile = blockIdx.x; tile < NTILES; tile += gridDim.x) {
        const int r0 = tile << 6;
        for (int i = t; i < 64 * 16; i += 256) {
            const int row = i >> 4, c16 = i & 15;
            const int rg = r0 + row;
            uint4 v = make_uint4(0, 0, 0, 0);
            if (rg < M) v = *(const uint4*)(Xb + (size_t)rg * HD + c16 * 8);
            *(uint4*)((char*)XsL + (((row << 8) + (c16 << 4)) ^ ((row & 7) << 4))) = v;
        }
        __syncthreads();

        bf16x8 a[4];
        #pragma unroll
        for (int ks = 0; ks < 4; ks++)
            a[ks] = *(const bf16x8*)((const char*)XsL + ((alin + ks * 64) ^ axor));

        f32x4 acc[8];
        #pragma unroll
        for (int ct = 0; ct < 8; ct++) {
            acc[ct][0] = 0.f; acc[ct][1] = 0.f; acc[ct][2] = 0.f; acc[ct][3] = 0.f;
        }
        #pragma unroll
        for (int ct = 0; ct < 8; ct++) {
            const int bn = ct * 16 + (lane & 15);
            #pragma unroll
            for (int ks = 0; ks < 4; ks++) {
                bf16x8 breg = *(const bf16x8*)((const char*)WsL +
                    (((bn << 8) + ks * 64 + ((lane >> 4) << 4)) ^ ((bn & 7) << 4)));
                acc[ct] = __builtin_amdgcn_mfma_f32_16x16x32_bf16(breg, a[ks], acc[ct], 0, 0, 0);
            }
        }

        const int orow = r0 + wave * 16 + (lane & 15);
        const bool rv = orow < M;
        float gdot = 0.f;
        const float ds = (degscale && rv) ? degscale[orow] : 1.f;
        #pragma unroll
        for (int ct = 0; ct < 8; ct++) {
            const int c0 = ct * 16 + cj;
            float v0 = acc[ct][0], v1 = acc[ct][1], v2 = acc[ct][2], v3 = acc[ct][3];
            if (bias) {
                v0 += bcol[ct].x * ds; v1 += bcol[ct].y * ds;
                v2 += bcol[ct].z * ds; v3 += bcol[ct].w * ds;
            }
            if (addend && rv) {
                ushort4 av = *(const ushort4*)(addend + (size_t)orow * HD + c0);
                v0 += bf2f(av.x); v1 += bf2f(av.y); v2 += bf2f(av.z); v3 += bf2f(av.w);
            }
            if (RELU) {
                v0 = fmaxf(v0, 0.f); v1 = fmaxf(v1, 0.f);
                v2 = fmaxf(v2, 0.f); v3 = fmaxf(v3, 0.f);
            }
            if (GATE) {
                gdot += v0 * gwv[ct].x + v1 * gwv[ct].y + v2 * gwv[ct].z + v3 * gwv[ct].w;
            } else if (rv) {
                ushort4 pk;
                pk.x = f2bf(v0); pk.y = f2bf(v1); pk.z = f2bf(v2); pk.w = f2bf(v3);
                *(ushort4*)(out + (size_t)orow * HD + c0) = pk;
            }
        }
        if (GATE) {
            gdot += __shfl_xor(gdot, 16, 64);
            gdot += __shfl_xor(gdot, 32, 64);
            if ((lane >> 4) == 0 && rv) gate[orow] = gdot + gb2[0];
        }
        __syncthreads();
    }
}

// ---------------------------------------------------------------------------
// Triple-output GEMM (R15 - measured good).
// ---------------------------------------------------------------------------
__global__ __launch_bounds__(256, 2) void pqtgemm_kernel(
    const u16* __restrict__ Xb, const u16* __restrict__ WtP,
    const u16* __restrict__ WtQ, const u16* __restrict__ WtT,
    const float* __restrict__ tb, u16* __restrict__ outP,
    u16* __restrict__ outQ, u16* __restrict__ outT, int M)
{
    __shared__ u16 WsL[2 * HD * HD];   // 64 KB swizzled weights (P|Q)
    __shared__ u16 XsL[64 * HD];       // 16 KB swizzled X tile
    const int t = threadIdx.x;
    const int lane = t & 63, wave = t >> 6;
    const int cj = ((lane >> 4) << 2);

    for (int i = t; i < 2 * HD * 16; i += 256) {
        const int w = i >> 11;               // HD*16 = 2048
        const int j = i & 2047;
        const int row = j >> 4, c16 = j & 15;
        const u16* Wt = w ? WtQ : WtP;
        uint4 v = *(const uint4*)(Wt + (size_t)row * HD + c16 * 8);
        *(uint4*)((char*)WsL + w * 32768 +
                  (((row << 8) + (c16 << 4)) ^ ((row & 7) << 4))) = v;
    }
    bf16x8 treg[8][4];
    #pragma unroll
    for (int ct = 0; ct < 8; ct++) {
        const int bn = ct * 16 + (lane & 15);
        #pragma unroll
        for (int ks = 0; ks < 4; ks++)
            treg[ct][ks] = *(const bf16x8*)(WtT + (size_t)bn * HD + ks * 32 + ((lane >> 4) << 3));
    }
    float4 tbc[8];
    #pragma unroll
    for (int ct = 0; ct < 8; ct++)
        tbc[ct] = *(const float4*)(tb + ct * 16 + cj);

    const int arow = wave * 16 + (lane & 15);
    const int alin = (arow << 8) + ((lane >> 4) << 4);
    const int axor = (arow & 7) << 4;
    __syncthreads();

    for (int tile = blockIdx.x; tile < NTILES; tile += gridDim.x) {
        const int r0 = tile << 6;
        for (int i = t; i < 64 * 16; i += 256) {
            const int row = i >> 4, c16 = i & 15;
            const int rg = r0 + row;
            uint4 v = make_uint4(0, 0, 0, 0);
            if (rg < M) v = *(const uint4*)(Xb + (size_t)rg * HD + c16 * 8);
            *(uint4*)((char*)XsL + (((row << 8) + (c16 << 4)) ^ ((row & 7) << 4))) = v;
        }
        __syncthreads();

        bf16x8 a[4];
        #pragma unroll
        for (int ks = 0; ks < 4; ks++)
            a[ks] = *(const bf16x8*)((const char*)XsL + ((alin + ks * 64) ^ axor));

        const int orow = r0 + wave * 16 + (lane & 15);
        const bool rv = orow < M;

        #pragma unroll
        for (int o = 0; o < 2; o++) {
            f32x4 acc[8];
            #pragma unroll
            for (int ct = 0; ct < 8; ct++) {
                acc[ct][0] = 0.f; acc[ct][1] = 0.f; acc[ct][2] = 0.f; acc[ct][3] = 0.f;
            }
            #pragma unroll
            for (int ct = 0; ct < 8; ct++) {
                const int bn = ct * 16 + (lane & 15);
                #pragma unroll
                for (int ks = 0; ks < 4; ks++) {
                    bf16x8 breg = *(const bf16x8*)((const char*)WsL + o * 32768 +
                        (((bn << 8) + ks * 64 + ((lane >> 4) << 4)) ^ ((bn & 7) << 4)));
                    acc[ct] = __builtin_amdgcn_mfma_f32_16x16x32_bf16(breg, a[ks], acc[ct], 0, 0, 0);
                }
            }
            if (rv) {
                u16* out = o ? outQ : outP;
                #pragma unroll
                for (int ct = 0; ct < 8; ct++) {
                    ushort4 pk;
                    pk.x = f2bf(acc[ct][0]); pk.y = f2bf(acc[ct][1]);
                    pk.z = f2bf(acc[ct][2]); pk.w = f2bf(acc[ct][3]);
                    *(ushort4*)(out + (size_t)orow * HD + ct * 16 + cj) = pk;
                }
            }
        }
        {
            f32x4 acc[8];
            #pragma unroll
            for (int ct = 0; ct < 8; ct++) {
                acc[ct][0] = 0.f; acc[ct][1] = 0.f; acc[ct][2] = 0.f; acc[ct][3] = 0.f;
            }
            #pragma unroll
            for (int ct = 0; ct < 8; ct++)
                #pragma unroll
                for (int ks = 0; ks < 4; ks++)
                    acc[ct] = __builtin_amdgcn_mfma_f32_16x16x32_bf16(treg[ct][ks], a[ks], acc[ct], 0, 0, 0);
            if (rv) {
                #pragma unroll
                for (int ct = 0; ct < 8; ct++) {
                    ushort4 pk;
                    pk.x = f2bf(acc[ct][0] + tbc[ct].x);
                    pk.y = f2bf(acc[ct][1] + tbc[ct].y);
                    pk.z = f2bf(acc[ct][2] + tbc[ct].z);
                    pk.w = f2bf(acc[ct][3] + tbc[ct].w);
                    *(ushort4*)(outT + (size_t)orow * HD + ct * 16 + cj) = pk;
                }
            }
        }
        __syncthreads();
    }
}

// ---------------------------------------------------------------------------
// Edge message pass: R18 structure with __launch_bounds__(256,3).
// Theory: unified VGPR+AGPR = 120+~56 = 176/wave > 170.7 (512/3) keeps us at
// 2 waves/SIMD; forcing min-3 makes the allocator shave the ~6-reg overshoot
// (LDS 47.6K x 3 = 142.8K fits).  Falsifier: FETCH/WRITE inflation = spills.
// ---------------------------------------------------------------------------
__global__ __launch_bounds__(256, 3) void edge_mfma_kernel(
    const float2* __restrict__ sef, const int* __restrict__ ssrc,
    const int* __restrict__ sdst, const int* __restrict__ off,
    const float* __restrict__ ew1, const float* __restrict__ eb1,
    const u16* __restrict__ Mt, const float* __restrict__ mvec,
    const u16* __restrict__ P, const u16* __restrict__ Q,
    u16* __restrict__ agg)
{
    __shared__ __align__(16) char XHT[HD * 72 * 2];   // 18 KB: XsL | HT | BNC
    __shared__ u16 PsL[64 * 136];    // 17 KB staged P rows
    __shared__ u16 QsL[32 * 136];    // 8.5 KB staged Q rows
    __shared__ u64 dlocL[8];         // 64 x u8 local-dst per tile
    __shared__ int nsrcL[2][64];     // 512 B double-buffered ssrc prefetch
    __shared__ float ew1L[2 * HD];
    __shared__ float eb1L[HD];
    __shared__ float mvL[HD];        // 512 B mvec (was 32 VGPRs)
    u16* HT = (u16*)XHT;
    const int t = threadIdx.x, lane = t & 63, wave = t >> 6;
    const int cj = (lane >> 4) << 2;
    const int n0 = blockIdx.x * 32;

    ew1L[t] = ew1[t];
    if (t < HD) { eb1L[t] = eb1[t]; mvL[t] = mvec[t]; }
    for (int i = t; i < 32 * 32; i += 256) {
        const int row = i >> 5, c4 = (i & 31) * 4;
        *(ushort4*)(QsL + row * 136 + c4) = *(const ushort4*)(Q + (size_t)(n0 + row) * HD + c4);
    }

    bf16x8 breg[8][4];
    #pragma unroll
    for (int ct = 0; ct < 8; ct++) {
        const int bn = ct * 16 + (lane & 15);
        #pragma unroll
        for (int ks = 0; ks < 4; ks++)
            breg[ct][ks] = *(const bf16x8*)(Mt + (size_t)bn * HD + ks * 32 + ((lane >> 4) << 3));
    }

    const int rt = wave & 1;
    const int c2b = (wave >> 1) * 4;
    const int nodeid = rt * 16 + (lane & 15);
    f32x4 acc2[4];
    #pragma unroll
    for (int i = 0; i < 4; i++) {
        acc2[i][0] = 0.f; acc2[i][1] = 0.f; acc2[i][2] = 0.f; acc2[i][3] = 0.f;
    }

    const int e0 = off[n0], e1 = off[n0 + 32];
    const int arow = wave * 16 + (lane & 15);
    const int alin = (arow << 8) + ((lane >> 4) << 4);
    const int axor = (arow & 7) << 4;
    const int el = wave * 16 + (lane & 15);
    if (t < 64) nsrcL[0][t] = (e0 + t < e1) ? ssrc[e0 + t] : 0;
    __syncthreads();

    int buf = 0;
    for (int base = e0; base < e1; base += 64) {
        for (int i = t; i < 64 * 16; i += 256) {
            const int row = i >> 4, c16 = i & 15;
            const int e = base + row;
            uint4 v = make_uint4(0, 0, 0, 0);
            uint4 pvv = make_uint4(0, 0, 0, 0);
            if (e < e1) {
                const float2 f = sef[e];
                const int c8 = c16 * 8;
                float o[8];
                #pragma unroll
                for (int k = 0; k < 8; k++)
                    o[k] = fmaxf(f.x * ew1L[c8 + k] + f.y * ew1L[HD + c8 + k] + eb1L[c8 + k], 0.f);
                v = make_uint4(pk2(o[0], o[1]), pk2(o[2], o[3]), pk2(o[4], o[5]), pk2(o[6], o[7]));
                const int srcI = nsrcL[buf][row];
                pvv = *(const uint4*)(P + (size_t)srcI * HD + c16 * 8);
            }
            *(uint4*)(XHT + (((row << 8) + (c16 << 4)) ^ ((row & 7) << 4))) = v;
            *(uint4*)(PsL + row * 136 + c16 * 8) = pvv;
        }
        if (t < 64) {
            const int e = base + t;
            ((unsigned char*)dlocL)[t] = (e < e1) ? (unsigned char)(sdst[e] - n0) : (unsigned char)0xFF;
            const int e2 = base + 64 + t;
            nsrcL[buf ^ 1][t] = (e2 < e1) ? ssrc[e2] : 0;
        }
        __syncthreads();

        bf16x8 a[4];
        #pragma unroll
        for (int ks = 0; ks < 4; ks++)
            a[ks] = *(const bf16x8*)(XHT + ((alin + ks * 64) ^ axor));
        const int e = base + el;
        const bool ev = e < e1;
        const int dl = ev ? (int)((const unsigned char*)dlocL)[el] : 0;
        __syncthreads();   // all XsL reads done before HT overwrite

        f32x4 acc[8];
        #pragma unroll
        for (int ct = 0; ct < 8; ct++) {
            acc[ct][0] = 0.f; acc[ct][1] = 0.f; acc[ct][2] = 0.f; acc[ct][3] = 0.f;
        }
        #pragma unroll
        for (int ct = 0; ct < 8; ct++)
            #pragma unroll
            for (int ks = 0; ks < 4; ks++)
                acc[ct] = __builtin_amdgcn_mfma_f32_16x16x32_bf16(breg[ct][ks], a[ks], acc[ct], 0, 0, 0);

        #pragma unroll
        for (int ct = 0; ct < 8; ct++) {
            const int c0 = ct * 16 + cj;
            float v0 = 0.f, v1 = 0.f, v2 = 0.f, v3 = 0.f;
            if (ev) {
                const ushort4 pvc = *(const ushort4*)(PsL + el * 136 + c0);
                const ushort4 qvc = *(const ushort4*)(QsL + dl * 136 + c0);
                const float4 mv = *(const float4*)(mvL + c0);
                v0 = fmaxf(acc[ct][0] + bf2f(pvc.x) + bf2f(qvc.x) + mv.x, 0.f);
                v1 = fmaxf(acc[ct][1] + bf2f(pvc.y) + bf2f(qvc.y) + mv.y, 0.f);
                v2 = fmaxf(acc[ct][2] + bf2f(pvc.z) + bf2f(qvc.z) + mv.z, 0.f);
                v3 = fmaxf(acc[ct][3] + bf2f(pvc.w) + bf2f(qvc.w) + mv.w, 0.f);
            }
            HT[(c0 + 0) * 72 + el] = f2bf(v0);
            HT[(c0 + 1) * 72 + el] = f2bf(v1);
            HT[(c0 + 2) * 72 + el] = f2bf(v2);
            HT[(c0 + 3) * 72 + el] = f2bf(v3);
        }
        __syncthreads();

        #pragma unroll
        for (int ks2 = 0; ks2 < 2; ks2++) {
            const u64 dv = dlocL[ks2 * 4 + (lane >> 4)];
            bf16x8 sfrag;
            #pragma unroll
            for (int j = 0; j < 8; j++) {
                const int dvj = (int)((dv >> (8 * j)) & 0xFF);
                sfrag[j] = (dvj == nodeid) ? (short)0x3F80 : (short)0;
            }
            #pragma unroll
            for (int i = 0; i < 4; i++) {
                const int col = (c2b + i) * 16 + (lane & 15);
                bf16x8 hfrag = *(const bf16x8*)(HT + col * 72 + ks2 * 32 + ((lane >> 4) << 3));
                acc2[i] = __builtin_amdgcn_mfma_f32_16x16x32_bf16(sfrag, hfrag, acc2[i], 0, 0, 0);
            }
        }
        __syncthreads();
        buf ^= 1;
    }

    u16* BNC = (u16*)XHT;
    #pragma unroll
    for (int i = 0; i < 4; i++) {
        const int col = (c2b + i) * 16 + (lane & 15);
        #pragma unroll
        for (int r = 0; r < 4; r++) {
            const int nl = rt * 16 + ((lane >> 4) << 2) + r;
            BNC[nl * 136 + col] = f2bf(acc2[i][r]);
        }
    }
    __syncthreads();
    for (int i = t; i < 32 * 16; i += 256) {
        const int row = i >> 4, c16 = i & 15;
        *(uint4*)(agg + (size_t)(n0 + row) * HD + c16 * 8) =
            *(const uint4*)(BNC + row * 136 + c16 * 8);
    }
}

// ---------------------------------------------------------------------------
// Batched weight folds + batched bias folds + wprep (R16 - measured good).
// ---------------------------------------------------------------------------
__global__ __launch_bounds__(256) void foldgemm_kernel(
    const float* __restrict__ ee_w2, const float* __restrict__ msg_w1,
    const float* __restrict__ msg_w2, const float* __restrict__ upd_w1,
    float* __restrict__ Mw, float* __restrict__ Mw2)
{
    __shared__ float Ws[HD * HD];
    __shared__ float Xs[32 * HD];
    const int m = blockIdx.x >> 2;
    const int l = m & 3;
    const float* X; const float* W; float* outp;
    if (m < 4) {
        X = ee_w2;
        W = msg_w1 + (size_t)l * 3 * HD2 + 2 * HD2;
        outp = Mw + (size_t)l * HD2;
    } else {
        X = msg_w2 + (size_t)l * HD2;
        W = upd_w1 + (size_t)l * 2 * HD2 + HD2;
        outp = Mw2 + (size_t)l * HD2;
    }
    const int t = threadIdx.x;
    for (int i = t; i < HD2 / 4; i += 256)
        ((float4*)Ws)[i] = ((const float4*)W)[i];
    const int c0 = (t & 31) * 4;
    const int rb = (t >> 5) * 4;
    const int r0 = (blockIdx.x & 3) * 32;
    for (int i = t; i < 32 * HD / 4; i += 256)
        ((float4*)Xs)[i] = ((const float4*)(X + (size_t)r0 * HD))[i];
    __syncthreads();
    float acc[4][4];
    #pragma unroll
    for (int a = 0; a < 4; a++)
        #pragma unroll
        for (int b = 0; b < 4; b++) acc[a][b] = 0.f;
    for (int k = 0; k < HD; k += 4) {
        float4 w0 = *(const float4*)(Ws + (k + 0) * HD + c0);
        float4 w1 = *(const float4*)(Ws + (k + 1) * HD + c0);
        float4 w2 = *(const float4*)(Ws + (k + 2) * HD + c0);
        float4 w3 = *(const float4*)(Ws + (k + 3) * HD + c0);
        #pragma unroll
        for (int rr = 0; rr < 4; rr++) {
            float4 xv = *(const float4*)(Xs + (rb + rr) * HD + k);
            acc[rr][0] += xv.x * w0.x + xv.y * w1.x + xv.z * w2.x + xv.w * w3.x;
            acc[rr][1] += xv.x * w0.y + xv.y * w1.y + xv.z * w2.y + xv.w * w3.y;
            acc[rr][2] += xv.x * w0.z + xv.y * w1.z + xv.z * w2.z + xv.w * w3.z;
            acc[rr][3] += xv.x * w0.w + xv.y * w1.w + xv.z * w2.w + xv.w * w3.w;
        }
    }
    #pragma unroll
    for (int rr = 0; rr < 4; rr++) {
        const int row = r0 + rb + rr;
        *(float4*)(outp + (size_t)row * HD + c0) =
            make_float4(acc[rr][0], acc[rr][1], acc[rr][2], acc[rr][3]);
    }
}

__global__ void mvecb_kernel(
    const float* __restrict__ ee_b2, const float* __restrict__ msg_w1,
    const float* __restrict__ msg_b1, const float* __restrict__ msg_b2,
    const float* __restrict__ upd_w1, float* __restrict__ mvec,
    float* __restrict__ b2u)
{
    const int m = blockIdx.x;
    const int l = m & 3;
    const int j = threadIdx.x;
    if (j >= HD) return;
    if (m < 4) {
        const float* W = msg_w1 + (size_t)l * 3 * HD2 + 2 * HD2;
        float s = msg_b1[(size_t)l * HD + j];
        for (int i = 0; i < HD; i++) s += ee_b2[i] * W[(size_t)i * HD + j];
        mvec[(size_t)l * HD + j] = s;
    } else {
        const float* W = upd_w1 + (size_t)l * 2 * HD2 + HD2;
        float s = 0.f;
        for (int i = 0; i < HD; i++) s += msg_b2[(size_t)l * HD + i] * W[(size_t)i * HD + j];
        b2u[(size_t)l * HD + j] = s;
    }
}

__global__ __launch_bounds__(256) void wprep_kernel(
    const float* __restrict__ msg_w1, const float* __restrict__ Mw2,
    const float* __restrict__ upd_w1, const float* __restrict__ upd_w2,
    const float* __restrict__ gw1, const float* __restrict__ ne_w2,
    const float* __restrict__ Mw, u16* __restrict__ wt)
{
    __shared__ float tileL[HD * (HD + 1)];
    const int b = blockIdx.x, t = threadIdx.x;
    const int l = b & 3;
    const float* S;
    if (b < 4)       S = msg_w1 + (size_t)l * 3 * HD2;
    else if (b < 8)  S = msg_w1 + (size_t)l * 3 * HD2 + HD2;
    else if (b < 12) S = Mw + (size_t)l * HD2;
    else if (b < 16) S = Mw2 + (size_t)l * HD2;
    else if (b < 20) S = upd_w1 + (size_t)l * 2 * HD2;
    else if (b < 24) S = upd_w1 + (size_t)l * 2 * HD2 + HD2;
    else if (b < 28) S = upd_w2 + (size_t)l * HD2;
    else if (b == 28) S = gw1;
    else             S = ne_w2;
    u16* D = wt + (size_t)b * HD2;
    for (int i = t; i < HD2; i += 256) {
        const int k = i >> 7, n = i & 127;
        tileL[k * (HD + 1) + n] = S[i];
    }
    __syncthreads();
    for (int i = t; i < HD2; i += 256) {
        const int n = i >> 7, k = i & 127;
        D[i] = f2bf(tileL[k * (HD + 1) + n]);
    }
}

// ---------------------------------------------------------------------------
// Node encoder layer 1 (7 -> 128), bf16 out.
// ---------------------------------------------------------------------------
__global__ __launch_bounds__(256) void ne1_kernel(
    const float* __restrict__ nf, const float* __restrict__ w1,
    const float* __restrict__ b1, u16* __restrict__ out)
{
    __shared__ float w1s[7 * HD];
    __shared__ float b1s[HD];
    const int t = threadIdx.x;
    for (int i = t; i < 7 * HD; i += 256) w1s[i] = w1[i];
    if (t < HD) b1s[t] = b1[t];
    __syncthreads();
    const int row = blockIdx.x * 32 + (t >> 3);
    const int c0 = (t & 7) * 16;
    if (row < NN) {
        float f[7];
        #pragma unroll
        for (int k = 0; k < 7; k++) f[k] = nf[(size_t)row * 7 + k];
        float o[16];
        #pragma unroll
        for (int c = 0; c < 16; c++) {
            float a = b1s[c0 + c];
            #pragma unroll
            for (int k = 0; k < 7; k++) a += f[k] * w1s[k * HD + c0 + c];
            o[c] = fmaxf(a, 0.f);
        }
        uint4 v0 = make_uint4(pk2(o[0], o[1]), pk2(o[2], o[3]), pk2(o[4], o[5]), pk2(o[6], o[7]));
        uint4 v1 = make_uint4(pk2(o[8], o[9]), pk2(o[10], o[11]), pk2(o[12], o[13]), pk2(o[14], o[15]));
        *(uint4*)(out + (size_t)row * HD + c0) = v0;
        *(uint4*)(out + (size_t)row * HD + c0 + 8) = v1;
    }
}

// ---------------------------------------------------------------------------
// CSR build.
// ---------------------------------------------------------------------------
__global__ void deg_count_kernel(const int* __restrict__ dst, int* __restrict__ deg) {
    const int i = blockIdx.x * 256 + threadIdx.x;
    if (i < NE) atomicAdd(&deg[dst[i]], 1);
}
__global__ void scan1_kernel(const int* __restrict__ deg, int* __restrict__ part) {
    __shared__ int s[256];
    const int t = threadIdx.x, i = blockIdx.x * 256 + t;
    s[t] = (i < NN) ? deg[i] : 0;
    __syncthreads();
    for (int d = 128; d > 0; d >>= 1) { if (t < d) s[t] += s[t + d]; __syncthreads(); }
    if (t == 0) part[blockIdx.x] = s[0];
}
__global__ void scan2_kernel(int* __restrict__ part, int nb) {
    if (threadIdx.x == 0 && blockIdx.x == 0) {
        int run = 0;
        for (int b = 0; b < nb; b++) { const int v = part[b]; part[b] = run; run += v; }
    }
}
__global__ void scan3_kernel(const int* __restrict__ deg, const int* __restrict__ part,
                             int* __restrict__ off, int* __restrict__ pos,
                             float* __restrict__ degf) {
    __shared__ int s[256];
    const int t = threadIdx.x, i = blockIdx.x * 256 + t;
    const int v = (i < NN) ? deg[i] : 0;
    s[t] = v;
    __syncthreads();
    for (int d = 1; d < 256; d <<= 1) {
        const int x = (t >= d) ? s[t - d] : 0;
        __syncthreads();
        s[t] += x;
        __syncthreads();
    }
    const int excl = s[t] - v + part[blockIdx.x];
    if (i < NN) {
        off[i] = excl; pos[i] = excl;
        degf[i] = (float)v;
        if (i == NN - 1) off[NN] = excl + v;
    }
}
__global__ void scatter_kernel(const int* __restrict__ src, const int* __restrict__ dst,
                               const float* __restrict__ ef, int* __restrict__ pos,
                               float2* __restrict__ sef, int* __restrict__ ssrc,
                               int* __restrict__ sdst) {
    const int e = blockIdx.x * 256 + threadIdx.x;
    if (e < NE) {
        const int d = dst[e];
        const int p = atomicAdd(&pos[d], 1);
        sef[p] = make_float2(ef[2 * e], ef[2 * e + 1]);
        ssrc[p] = src[e]; sdst[p] = d;
    }
}

__global__ void bounds_kernel(const int* __restrict__ gid, int* __restrict__ gs) {
    const int g = threadIdx.x;
    if (g <= NG) {
        int lo = 0, hi = NN;
        while (lo < hi) {
            const int mid = (lo + hi) >> 1;
            if (gid[mid] < g) lo = mid + 1; else hi = mid;
        }
        gs[g] = lo;
    }
}

// ---------------------------------------------------------------------------
// Pooling (3-stage) + policy head (measured good).
// ---------------------------------------------------------------------------
__global__ __launch_bounds__(256) void poolA_kernel(
    const float* __restrict__ gate, const int* __restrict__ gs,
    float* __restrict__ ex, float* __restrict__ gz)
{
    __shared__ float red[256];
    const int g = blockIdx.x, t = threadIdx.x;
    const int s = gs[g], e = gs[g + 1];
    if (s >= e) {
        if (t == 0) gz[g] = 1.f;
        return;
    }
    float m = -3.4e38f;
    for (int i = s + t; i < e; i += 256) m = fmaxf(m, gate[i]);
    red[t] = m; __syncthreads();
    for (int d = 128; d > 0; d >>= 1) {
        if (t < d) red[t] = fmaxf(red[t], red[t + d]);
        __syncthreads();
    }
    const float gm = red[0];
    __syncthreads();
    float zs = 0.f;
    for (int i = s + t; i < e; i += 256) {
        const float ev = expf(gate[i] - gm);
        ex[i] = ev; zs += ev;
    }
    red[t] = zs; __syncthreads();
    for (int d = 128; d > 0; d >>= 1) {
        if (t < d) red[t] += red[t + d];
        __syncthreads();
    }
    if (t == 0) gz[g] = red[0];
}

__global__ __launch_bounds__(256) void poolB_kernel(
    const float* __restrict__ ex, const int* __restrict__ gs,
    const u16* __restrict__ hb, float* __restrict__ partial)
{
    __shared__ float redL[16][132];
    const int b = blockIdx.x;
    const int g = b / PSLICE, sl = b % PSLICE;
    const int lo = gs[g], hi = gs[g + 1];
    const int len = hi - lo;
    const int chunk = (len + PSLICE - 1) / PSLICE;
    const int ns = lo + sl * chunk;
    const int ne = min(ns + chunk, hi);
    const int t = threadIdx.x;
    const int c8 = (t & 15) * 8;
    const int ro = t >> 4;
    float acc[8] = {0.f, 0.f, 0.f, 0.f, 0.f, 0.f, 0.f, 0.f};
    for (int n = ns + ro; n < ne; n += 16) {
        const float w = ex[n];
        const ushort4 h0 = *(const ushort4*)(hb + (size_t)n * HD + c8);
        const ushort4 h1 = *(const ushort4*)(hb + (size_t)n * HD + c8 + 4);
        acc[0] += w * bf2f(h0.x); acc[1] += w * bf2f(h0.y);
        acc[2] += w * bf2f(h0.z); acc[3] += w * bf2f(h0.w);
        acc[4] += w * bf2f(h1.x); acc[5] += w * bf2f(h1.y);
        acc[6] += w * bf2f(h1.z); acc[7] += w * bf2f(h1.w);
    }
    #pragma unroll
    for (int j = 0; j < 8; j++) redL[ro][c8 + j] = acc[j];
    __syncthreads();
    if (t < HD) {
        float s = 0.f;
        #pragma unroll
        for (int r = 0; r < 16; r++) s += redL[r][t];
        partial[(size_t)b * HD + t] = s;
    }
}

__global__ void poolC_kernel(const float* __restrict__ partial,
                             const float* __restrict__ gz,
                             float* __restrict__ emb)
{
    const int g = blockIdx.x, t = threadIdx.x;
    float s = 0.f;
    #pragma unroll
    for (int sl = 0; sl < PSLICE; sl++)
        s += partial[(size_t)(g * PSLICE + sl) * HD + t];
    emb[(size_t)g * HD + t] = s / gz[g];
}

__global__ __launch_bounds__(256) void policy_kernel(
    const float* __restrict__ emb,
    const float* __restrict__ w1, const float* __restrict__ b1,
    const float* __restrict__ w2, const float* __restrict__ b2,
    const float* __restrict__ w3, const float* __restrict__ b3,
    float* __restrict__ out)
{
    __shared__ float A[NG * HD];
    __shared__ float Bs[NG * HD];
    const int t = threadIdx.x;
    for (int i = t; i < NG * HD / 4; i += 256)
        ((float4*)A)[i] = ((const float4*)emb)[i];
    __syncthreads();
    const int c0 = (t & 31) * 4;
    const int rb = (t >> 5) * 8;
    {
        float4 bv = *(const float4*)(b1 + c0);
        for (int rr = 0; rr < 8; rr++) {
            const int r = rb + rr;
            float a0 = bv.x, a1 = bv.y, a2 = bv.z, a3 = bv.w;
            for (int k = 0; k < HD; k++) {
                const float x = A[r * HD + k];
                float4 wv = *(const float4*)(w1 + k * HD + c0);
                a0 += x * wv.x; a1 += x * wv.y; a2 += x * wv.z; a3 += x * wv.w;
            }
            *(float4*)(Bs + r * HD + c0) =
                make_float4(fmaxf(a0, 0.f), fmaxf(a1, 0.f), fmaxf(a2, 0.f), fmaxf(a3, 0.f));
        }
    }
    __syncthreads();
    {
        float4 bv = *(const float4*)(b2 + c0);
        for (int rr = 0; rr < 8; rr++) {
            const int r = rb + rr;
            float a0 = bv.x, a1 = bv.y, a2 = bv.z, a3 = bv.w;
            for (int k = 0; k < HD; k++) {
                const float x = Bs[r * HD + k];
                float4 wv = *(const float4*)(w2 + k * HD + c0);
                a0 += x * wv.x; a1 += x * wv.y; a2 += x * wv.z; a3 += x * wv.w;
            }
            *(float4*)(A + r * HD + c0) =
                make_float4(fmaxf(a0, 0.f), fmaxf(a1, 0.f), fmaxf(a2, 0.f), fmaxf(a3, 0.f));
        }
    }
    __syncthreads();
    {
        float4 bv = *(const float4*)(b3 + c0);
        for (int rr = 0; rr < 8; rr++) {
            const int r = rb + rr;
            float a[4] = {bv.x, bv.y, bv.z, bv.w};
            for (int k = 0; k < HD; k++) {
                const float x = A[r * HD + k];
                float4 wv = *(const float4*)(w3 + k * HD + c0);
                a[0] += x * wv.x; a[1] += x * wv.y; a[2] += x * wv.z; a[3] += x * wv.w;
            }
            #pragma unroll
            for (int j = 0; j < 4; j++) {
                const int c = c0 + j;
                if (c < 64) {
                    out[r * 64 + c] = a[j];
                } else {
                    const float ls = fminf(fmaxf(a[j], -20.f), 2.f);
                    out[4096 + r * 64 + (c - 64)] = expf(ls);
                }
            }
        }
    }
}

// ---------------------------------------------------------------------------
extern "C" void kernel_launch(void* const* d_in, const int* in_sizes, int n_in,
                              void* d_out, int out_size, void* d_ws, size_t ws_size,
                              hipStream_t stream) {
    const float* node_feat = (const float*)d_in[0];
    const float* edge_feat = (const float*)d_in[1];
    const float* ne_w1 = (const float*)d_in[2];
    const float* ne_b1 = (const float*)d_in[3];
    const float* ne_w2 = (const float*)d_in[4];
    const float* ne_b2 = (const float*)d_in[5];
    const float* ee_w1 = (const float*)d_in[6];
    const float* ee_b1 = (const float*)d_in[7];
    const float* ee_w2 = (const float*)d_in[8];
    const float* ee_b2 = (const float*)d_in[9];
    const float* msg_w1 = (const float*)d_in[10];
    const float* msg_b1 = (const float*)d_in[11];
    const float* msg_w2 = (const float*)d_in[12];
    const float* msg_b2 = (const float*)d_in[13];
    const float* upd_w1 = (const float*)d_in[14];
    const float* upd_b1 = (const float*)d_in[15];
    const float* upd_w2 = (const float*)d_in[16];
    const float* upd_b2 = (const float*)d_in[17];
    const float* gate_w1 = (const float*)d_in[18];
    const float* gate_b1 = (const float*)d_in[19];
    const float* gate_w2 = (const float*)d_in[20];
    const float* gate_b2 = (const float*)d_in[21];
    const float* pol_w1 = (const float*)d_in[22];
    const float* pol_b1 = (const float*)d_in[23];
    const float* pol_w2 = (const float*)d_in[24];
    const float* pol_b2 = (const float*)d_in[25];
    const float* pol_w3 = (const float*)d_in[26];
    const float* pol_b3 = (const float*)d_in[27];
    const int* src = (const int*)d_in[28];
    const int* dst = (const int*)d_in[29];
    const int* gid = (const int*)d_in[30];

    // ---- workspace layout (~143 MB) ----
    char* p = (char*)d_ws;
    u16* hb   = (u16*)p;    p += (size_t)NN * HD * 2;
    u16* Pb   = (u16*)p;    p += (size_t)NN * HD * 2;
    u16* Qb   = (u16*)p;    p += (size_t)NN * HD * 2;
    u16* aggb = (u16*)p;    p += (size_t)NN * HD * 2;
    u16* tub  = (u16*)p;    p += (size_t)NN * HD * 2;
    float2* sef = (float2*)p; p += (size_t)NE * 8;
    int* ssrc = (int*)p;    p += (size_t)NE * 4;
    int* sdst = (int*)p;    p += (size_t)NE * 4;
    int* off  = (int*)p;    p += (size_t)(NN + 4) * 4;
    int* pos  = (int*)p;    p += (size_t)NN * 4;
    int* deg  = (int*)p;    p += (size_t)NN * 4;
    float* degf = (float*)p; p += (size_t)NN * 4;
    float* gate = (float*)p; p += (size_t)NN * 4;
    float* ex   = (float*)p; p += (size_t)NN * 4;
    int* part = (int*)p;    p += 2048;
    int* gs   = (int*)p;    p += 512;
    float* gz   = (float*)p; p += 256;
    float* emb = (float*)p; p += (size_t)NG * HD * 4;
    float* partialP = (float*)p; p += (size_t)NG * PSLICE * HD * 4;
    float* Mw  = (float*)p; p += (size_t)NLAYER * HD2 * 4;
    float* Mw2 = (float*)p; p += (size_t)NLAYER * HD2 * 4;
    float* mvec = (float*)p; p += (size_t)NLAYER * HD * 4;
    float* b2u  = (float*)p; p += (size_t)NLAYER * HD * 4;
    u16* wt = (u16*)p;      p += (size_t)30 * HD2 * 2;

    // ---- CSR build ----
    hipMemsetAsync(deg, 0, (size_t)NN * 4, stream);
    deg_count_kernel<<<(NE + 255) / 256, 256, 0, stream>>>(dst, deg);
    scan1_kernel<<<SCAN_NB, 256, 0, stream>>>(deg, part);
    scan2_kernel<<<1, 64, 0, stream>>>(part, SCAN_NB);
    scan3_kernel<<<SCAN_NB, 256, 0, stream>>>(deg, part, off, pos, degf);
    scatter_kernel<<<(NE + 255) / 256, 256, 0, stream>>>(src, dst, edge_feat, pos, sef, ssrc, sdst);
    bounds_kernel<<<1, 128, 0, stream>>>(gid, gs);

    // ---- weight folds (batched) + prep ----
    foldgemm_kernel<<<32, 256, 0, stream>>>(ee_w2, msg_w1, msg_w2, upd_w1, Mw, Mw2);
    mvecb_kernel<<<8, 128, 0, stream>>>(ee_b2, msg_w1, msg_b1, msg_b2, upd_w1, mvec, b2u);
    wprep_kernel<<<30, 256, 0, stream>>>(msg_w1, Mw2, upd_w1, upd_w2, gate_w1, ne_w2, Mw, wt);

    // ---- node encoder ----
    ne1_kernel<<<3125, 256, 0, stream>>>(node_feat, ne_w1, ne_b1, Pb);
    mgemm_kernel<false, false><<<512, 256, 0, stream>>>(
        Pb, wt + (size_t)29 * HD2, ne_b2, nullptr, nullptr, hb, NN, nullptr, nullptr, nullptr);

    // ---- message-passing layers (4 dispatches/layer, R16 structure) ----
    for (int l = 0; l < NLAYER; l++) {
        pqtgemm_kernel<<<512, 256, 0, stream>>>(
            hb, wt + (size_t)(0 + l) * HD2, wt + (size_t)(4 + l) * HD2,
            wt + (size_t)(16 + l) * HD2, upd_b1 + (size_t)l * HD, Pb, Qb, tub, NN);
        edge_mfma_kernel<<<NN / 32, 256, 0, stream>>>(sef, ssrc, sdst, off, ee_w1, ee_b1,
            wt + (size_t)(8 + l) * HD2, mvec + (size_t)l * HD, Pb, Qb, aggb);
        mgemm_kernel<true, false><<<512, 256, 0, stream>>>(
            aggb, wt + (size_t)(12 + l) * HD2, b2u + (size_t)l * HD, degf, tub, Pb, NN,
            nullptr, nullptr, nullptr);
        mgemm_kernel<false, false><<<512, 256, 0, stream>>>(
            Pb, wt + (size_t)(24 + l) * HD2, upd_b2 + (size_t)l * HD, nullptr, hb, hb, NN,
            nullptr, nullptr, nullptr);
    }

    // ---- gate (fused dot) + pooling (3-stage) + policy ----
    mgemm_kernel<true, true><<<512, 256, 0, stream>>>(
        hb, wt + (size_t)28 * HD2, gate_b1, nullptr, nullptr, nullptr, NN,
        gate_w2, gate_b2, gate);
    poolA_kernel<<<NG, 256, 0, stream>>>(gate, gs, ex, gz);
    poolB_kernel<<<NG * PSLICE, 256, 0, stream>>>(ex, gs, hb, partialP);
    poolC_kernel<<<NG, 128, 0, stream>>>(partialP, gz, emb);
    policy_kernel<<<1, 256, 0, stream>>>(emb, pol_w1, pol_b1, pol_w2, pol_b2, pol_w3, pol_b3, (float*)d_out);
}

// Round 20
// 1521.225 us; speedup vs baseline: 1.0545x; 1.0545x over previous
//
#include <hip/hip_runtime.h>
#include <stdint.h>

#define NN 100000
#define NE 600000
#define NG 64
#define HD 128
#define HD2 (HD*HD)
#define NLAYER 4
#define SCAN_NB 391   // ceil(NN/256)
#define NTILES ((NN + 63) / 64)
#define PSLICE 16

typedef unsigned short u16;
typedef unsigned int u32;
typedef unsigned long long u64;
typedef __attribute__((ext_vector_type(8))) short bf16x8;   // 8 bf16 = 4 VGPR
typedef __attribute__((ext_vector_type(4))) float f32x4;

__device__ __forceinline__ float bf2f(u32 v) { return __uint_as_float(v << 16); }
__device__ __forceinline__ u16 f2bf(float f) {
    u32 u = __float_as_uint(f);
    return (u16)((u + 0x7FFFu + ((u >> 16) & 1u)) >> 16);
}
__device__ __forceinline__ u32 pk2(float a, float b) {
    return (u32)f2bf(a) | ((u32)f2bf(b) << 16);
}

// ---------------------------------------------------------------------------
// MFMA GEMM (measured good - unchanged, grid 512).
// ---------------------------------------------------------------------------
template<bool RELU, bool GATE>
__global__ __launch_bounds__(256, 3) void mgemm_kernel(
    const u16* __restrict__ Xb, const u16* __restrict__ Wt,
    const float* __restrict__ bias, const float* __restrict__ degscale,
    const u16* __restrict__ addend, u16* __restrict__ out, int M,
    const float* __restrict__ gw2, const float* __restrict__ gb2,
    float* __restrict__ gate)
{
    __shared__ u16 WsL[HD * HD];   // 32 KB swizzled weights
    __shared__ u16 XsL[64 * HD];   // 16 KB swizzled X tile
    const int t = threadIdx.x;
    const int lane = t & 63, wave = t >> 6;
    const int cj = ((lane >> 4) << 2);

    for (int i = t; i < HD * 16; i += 256) {
        const int row = i >> 4, c16 = i & 15;
        uint4 v = *(const uint4*)(Wt + (size_t)row * HD + c16 * 8);
        *(uint4*)((char*)WsL + (((row << 8) + (c16 << 4)) ^ ((row & 7) << 4))) = v;
    }
    float4 bcol[8];
    #pragma unroll
    for (int ct = 0; ct < 8; ct++)
        bcol[ct] = bias ? *(const float4*)(bias + ct * 16 + cj)
                        : make_float4(0.f, 0.f, 0.f, 0.f);
    float4 gwv[8];
    if (GATE) {
        #pragma unroll
        for (int ct = 0; ct < 8; ct++)
            gwv[ct] = *(const float4*)(gw2 + ct * 16 + cj);
    }

    const int arow = wave * 16 + (lane & 15);
    const int alin = (arow << 8) + ((lane >> 4) << 4);
    const int axor = (arow & 7) << 4;
    __syncthreads();

    for (int tile = blockIdx.x; tile < NTILES; tile += gridDim.x) {
        const int r0 = tile << 6;
        for (int i = t; i < 64 * 16; i += 256) {
            const int row = i >> 4, c16 = i & 15;
            const int rg = r0 + row;
            uint4 v = make_uint4(0, 0, 0, 0);
            if (rg < M) v = *(const uint4*)(Xb + (size_t)rg * HD + c16 * 8);
            *(uint4*)((char*)XsL + (((row << 8) + (c16 << 4)) ^ ((row & 7) << 4))) = v;
        }
        __syncthreads();

        bf16x8 a[4];
        #pragma unroll
        for (int ks = 0; ks < 4; ks++)
            a[ks] = *(const bf16x8*)((const char*)XsL + ((alin + ks * 64) ^ axor));

        f32x4 acc[8];
        #pragma unroll
        for (int ct = 0; ct < 8; ct++) {
            acc[ct][0] = 0.f; acc[ct][1] = 0.f; acc[ct][2] = 0.f; acc[ct][3] = 0.f;
        }
        #pragma unroll
        for (int ct = 0; ct < 8; ct++) {
            const int bn = ct * 16 + (lane & 15);
            #pragma unroll
            for (int ks = 0; ks < 4; ks++) {
                bf16x8 breg = *(const bf16x8*)((const char*)WsL +
                    (((bn << 8) + ks * 64 + ((lane >> 4) << 4)) ^ ((bn & 7) << 4)));
                acc[ct] = __builtin_amdgcn_mfma_f32_16x16x32_bf16(breg, a[ks], acc[ct], 0, 0, 0);
            }
        }

        const int orow = r0 + wave * 16 + (lane & 15);
        const bool rv = orow < M;
        float gdot = 0.f;
        const float ds = (degscale && rv) ? degscale[orow] : 1.f;
        #pragma unroll
        for (int ct = 0; ct < 8; ct++) {
            const int c0 = ct * 16 + cj;
            float v0 = acc[ct][0], v1 = acc[ct][1], v2 = acc[ct][2], v3 = acc[ct][3];
            if (bias) {
                v0 += bcol[ct].x * ds; v1 += bcol[ct].y * ds;
                v2 += bcol[ct].z * ds; v3 += bcol[ct].w * ds;
            }
            if (addend && rv) {
                ushort4 av = *(const ushort4*)(addend + (size_t)orow * HD + c0);
                v0 += bf2f(av.x); v1 += bf2f(av.y); v2 += bf2f(av.z); v3 += bf2f(av.w);
            }
            if (RELU) {
                v0 = fmaxf(v0, 0.f); v1 = fmaxf(v1, 0.f);
                v2 = fmaxf(v2, 0.f); v3 = fmaxf(v3, 0.f);
            }
            if (GATE) {
                gdot += v0 * gwv[ct].x + v1 * gwv[ct].y + v2 * gwv[ct].z + v3 * gwv[ct].w;
            } else if (rv) {
                ushort4 pk;
                pk.x = f2bf(v0); pk.y = f2bf(v1); pk.z = f2bf(v2); pk.w = f2bf(v3);
                *(ushort4*)(out + (size_t)orow * HD + c0) = pk;
            }
        }
        if (GATE) {
            gdot += __shfl_xor(gdot, 16, 64);
            gdot += __shfl_xor(gdot, 32, 64);
            if ((lane >> 4) == 0 && rv) gate[orow] = gdot + gb2[0];
        }
        __syncthreads();
    }
}

// ---------------------------------------------------------------------------
// Triple-output GEMM (R15 - measured good).
// ---------------------------------------------------------------------------
__global__ __launch_bounds__(256, 2) void pqtgemm_kernel(
    const u16* __restrict__ Xb, const u16* __restrict__ WtP,
    const u16* __restrict__ WtQ, const u16* __restrict__ WtT,
    const float* __restrict__ tb, u16* __restrict__ outP,
    u16* __restrict__ outQ, u16* __restrict__ outT, int M)
{
    __shared__ u16 WsL[2 * HD * HD];   // 64 KB swizzled weights (P|Q)
    __shared__ u16 XsL[64 * HD];       // 16 KB swizzled X tile
    const int t = threadIdx.x;
    const int lane = t & 63, wave = t >> 6;
    const int cj = ((lane >> 4) << 2);

    for (int i = t; i < 2 * HD * 16; i += 256) {
        const int w = i >> 11;               // HD*16 = 2048
        const int j = i & 2047;
        const int row = j >> 4, c16 = j & 15;
        const u16* Wt = w ? WtQ : WtP;
        uint4 v = *(const uint4*)(Wt + (size_t)row * HD + c16 * 8);
        *(uint4*)((char*)WsL + w * 32768 +
                  (((row << 8) + (c16 << 4)) ^ ((row & 7) << 4))) = v;
    }
    bf16x8 treg[8][4];
    #pragma unroll
    for (int ct = 0; ct < 8; ct++) {
        const int bn = ct * 16 + (lane & 15);
        #pragma unroll
        for (int ks = 0; ks < 4; ks++)
            treg[ct][ks] = *(const bf16x8*)(WtT + (size_t)bn * HD + ks * 32 + ((lane >> 4) << 3));
    }
    float4 tbc[8];
    #pragma unroll
    for (int ct = 0; ct < 8; ct++)
        tbc[ct] = *(const float4*)(tb + ct * 16 + cj);

    const int arow = wave * 16 + (lane & 15);
    const int alin = (arow << 8) + ((lane >> 4) << 4);
    const int axor = (arow & 7) << 4;
    __syncthreads();

    for (int tile = blockIdx.x; tile < NTILES; tile += gridDim.x) {
        const int r0 = tile << 6;
        for (int i = t; i < 64 * 16; i += 256) {
            const int row = i >> 4, c16 = i & 15;
            const int rg = r0 + row;
            uint4 v = make_uint4(0, 0, 0, 0);
            if (rg < M) v = *(const uint4*)(Xb + (size_t)rg * HD + c16 * 8);
            *(uint4*)((char*)XsL + (((row << 8) + (c16 << 4)) ^ ((row & 7) << 4))) = v;
        }
        __syncthreads();

        bf16x8 a[4];
        #pragma unroll
        for (int ks = 0; ks < 4; ks++)
            a[ks] = *(const bf16x8*)((const char*)XsL + ((alin + ks * 64) ^ axor));

        const int orow = r0 + wave * 16 + (lane & 15);
        const bool rv = orow < M;

        #pragma unroll
        for (int o = 0; o < 2; o++) {
            f32x4 acc[8];
            #pragma unroll
            for (int ct = 0; ct < 8; ct++) {
                acc[ct][0] = 0.f; acc[ct][1] = 0.f; acc[ct][2] = 0.f; acc[ct][3] = 0.f;
            }
            #pragma unroll
            for (int ct = 0; ct < 8; ct++) {
                const int bn = ct * 16 + (lane & 15);
                #pragma unroll
                for (int ks = 0; ks < 4; ks++) {
                    bf16x8 breg = *(const bf16x8*)((const char*)WsL + o * 32768 +
                        (((bn << 8) + ks * 64 + ((lane >> 4) << 4)) ^ ((bn & 7) << 4)));
                    acc[ct] = __builtin_amdgcn_mfma_f32_16x16x32_bf16(breg, a[ks], acc[ct], 0, 0, 0);
                }
            }
            if (rv) {
                u16* out = o ? outQ : outP;
                #pragma unroll
                for (int ct = 0; ct < 8; ct++) {
                    ushort4 pk;
                    pk.x = f2bf(acc[ct][0]); pk.y = f2bf(acc[ct][1]);
                    pk.z = f2bf(acc[ct][2]); pk.w = f2bf(acc[ct][3]);
                    *(ushort4*)(out + (size_t)orow * HD + ct * 16 + cj) = pk;
                }
            }
        }
        {
            f32x4 acc[8];
            #pragma unroll
            for (int ct = 0; ct < 8; ct++) {
                acc[ct][0] = 0.f; acc[ct][1] = 0.f; acc[ct][2] = 0.f; acc[ct][3] = 0.f;
            }
            #pragma unroll
            for (int ct = 0; ct < 8; ct++)
                #pragma unroll
                for (int ks = 0; ks < 4; ks++)
                    acc[ct] = __builtin_amdgcn_mfma_f32_16x16x32_bf16(treg[ct][ks], a[ks], acc[ct], 0, 0, 0);
            if (rv) {
                #pragma unroll
                for (int ct = 0; ct < 8; ct++) {
                    ushort4 pk;
                    pk.x = f2bf(acc[ct][0] + tbc[ct].x);
                    pk.y = f2bf(acc[ct][1] + tbc[ct].y);
                    pk.z = f2bf(acc[ct][2] + tbc[ct].z);
                    pk.w = f2bf(acc[ct][3] + tbc[ct].w);
                    *(ushort4*)(outT + (size_t)orow * HD + ct * 16 + cj) = pk;
                }
            }
        }
        __syncthreads();
    }
}

// ---------------------------------------------------------------------------
// Edge message pass: (256,3) forced, with live-set cut to fit 3 waves/SIMD:
//  - main MFMA chunked into 2 halves of 4 ct (acc peak 32 -> 16 regs)
//  - A-frags re-read from LDS per half (removes 16 live regs during MFMA)
// R19 proved occupancy rises to 29% when regs fit; this makes them fit.
// Falsifier: FETCH/WRITE inflation (spills) -> revert to R18, declare done.
// ---------------------------------------------------------------------------
__global__ __launch_bounds__(256, 3) void edge_mfma_kernel(
    const float2* __restrict__ sef, const int* __restrict__ ssrc,
    const int* __restrict__ sdst, const int* __restrict__ off,
    const float* __restrict__ ew1, const float* __restrict__ eb1,
    const u16* __restrict__ Mt, const float* __restrict__ mvec,
    const u16* __restrict__ P, const u16* __restrict__ Q,
    u16* __restrict__ agg)
{
    __shared__ __align__(16) char XHT[HD * 72 * 2];   // 18 KB: XsL | HT | BNC
    __shared__ u16 PsL[64 * 136];    // 17 KB staged P rows
    __shared__ u16 QsL[32 * 136];    // 8.5 KB staged Q rows
    __shared__ u64 dlocL[8];         // 64 x u8 local-dst per tile
    __shared__ int nsrcL[2][64];     // 512 B double-buffered ssrc prefetch
    __shared__ float ew1L[2 * HD];
    __shared__ float eb1L[HD];
    __shared__ float mvL[HD];        // 512 B mvec
    u16* HT = (u16*)XHT;
    const int t = threadIdx.x, lane = t & 63, wave = t >> 6;
    const int cj = (lane >> 4) << 2;
    const int n0 = blockIdx.x * 32;

    ew1L[t] = ew1[t];
    if (t < HD) { eb1L[t] = eb1[t]; mvL[t] = mvec[t]; }
    for (int i = t; i < 32 * 32; i += 256) {
        const int row = i >> 5, c4 = (i & 31) * 4;
        *(ushort4*)(QsL + row * 136 + c4) = *(const ushort4*)(Q + (size_t)(n0 + row) * HD + c4);
    }

    bf16x8 breg[8][4];
    #pragma unroll
    for (int ct = 0; ct < 8; ct++) {
        const int bn = ct * 16 + (lane & 15);
        #pragma unroll
        for (int ks = 0; ks < 4; ks++)
            breg[ct][ks] = *(const bf16x8*)(Mt + (size_t)bn * HD + ks * 32 + ((lane >> 4) << 3));
    }

    const int rt = wave & 1;
    const int c2b = (wave >> 1) * 4;
    const int nodeid = rt * 16 + (lane & 15);
    f32x4 acc2[4];
    #pragma unroll
    for (int i = 0; i < 4; i++) {
        acc2[i][0] = 0.f; acc2[i][1] = 0.f; acc2[i][2] = 0.f; acc2[i][3] = 0.f;
    }

    const int e0 = off[n0], e1 = off[n0 + 32];
    const int arow = wave * 16 + (lane & 15);
    const int alin = (arow << 8) + ((lane >> 4) << 4);
    const int axor = (arow & 7) << 4;
    const int el = wave * 16 + (lane & 15);
    if (t < 64) nsrcL[0][t] = (e0 + t < e1) ? ssrc[e0 + t] : 0;
    __syncthreads();

    int buf = 0;
    for (int base = e0; base < e1; base += 64) {
        for (int i = t; i < 64 * 16; i += 256) {
            const int row = i >> 4, c16 = i & 15;
            const int e = base + row;
            uint4 v = make_uint4(0, 0, 0, 0);
            uint4 pvv = make_uint4(0, 0, 0, 0);
            if (e < e1) {
                const float2 f = sef[e];
                const int c8 = c16 * 8;
                float o[8];
                #pragma unroll
                for (int k = 0; k < 8; k++)
                    o[k] = fmaxf(f.x * ew1L[c8 + k] + f.y * ew1L[HD + c8 + k] + eb1L[c8 + k], 0.f);
                v = make_uint4(pk2(o[0], o[1]), pk2(o[2], o[3]), pk2(o[4], o[5]), pk2(o[6], o[7]));
                const int srcI = nsrcL[buf][row];
                pvv = *(const uint4*)(P + (size_t)srcI * HD + c16 * 8);
            }
            *(uint4*)(XHT + (((row << 8) + (c16 << 4)) ^ ((row & 7) << 4))) = v;
            *(uint4*)(PsL + row * 136 + c16 * 8) = pvv;
        }
        if (t < 64) {
            const int e = base + t;
            ((unsigned char*)dlocL)[t] = (e < e1) ? (unsigned char)(sdst[e] - n0) : (unsigned char)0xFF;
            const int e2 = base + 64 + t;
            nsrcL[buf ^ 1][t] = (e2 < e1) ? ssrc[e2] : 0;
        }
        __syncthreads();

        const int e = base + el;
        const bool ev = e < e1;
        const int dl = ev ? (int)((const unsigned char*)dlocL)[el] : 0;

        // ---- phase 3 (chunked): two halves of 4 ct each; acc consumed
        //      into HT immediately; A-frags re-read per half from LDS ----
        #pragma unroll
        for (int half = 0; half < 2; half++) {
            bf16x8 a[4];
            #pragma unroll
            for (int ks = 0; ks < 4; ks++)
                a[ks] = *(const bf16x8*)(XHT + ((alin + ks * 64) ^ axor));

            f32x4 acc[4];
            #pragma unroll
            for (int c = 0; c < 4; c++) {
                acc[c][0] = 0.f; acc[c][1] = 0.f; acc[c][2] = 0.f; acc[c][3] = 0.f;
            }
            #pragma unroll
            for (int c = 0; c < 4; c++)
                #pragma unroll
                for (int ks = 0; ks < 4; ks++)
                    acc[c] = __builtin_amdgcn_mfma_f32_16x16x32_bf16(
                        breg[half * 4 + c][ks], a[ks], acc[c], 0, 0, 0);

            #pragma unroll
            for (int c = 0; c < 4; c++) {
                const int c0 = (half * 4 + c) * 16 + cj;
                float v0 = 0.f, v1 = 0.f, v2 = 0.f, v3 = 0.f;
                if (ev) {
                    const ushort4 pvc = *(const ushort4*)(PsL + el * 136 + c0);
                    const ushort4 qvc = *(const ushort4*)(QsL + dl * 136 + c0);
                    const float4 mv = *(const float4*)(mvL + c0);
                    v0 = fmaxf(acc[c][0] + bf2f(pvc.x) + bf2f(qvc.x) + mv.x, 0.f);
                    v1 = fmaxf(acc[c][1] + bf2f(pvc.y) + bf2f(qvc.y) + mv.y, 0.f);
                    v2 = fmaxf(acc[c][2] + bf2f(pvc.z) + bf2f(qvc.z) + mv.z, 0.f);
                    v3 = fmaxf(acc[c][3] + bf2f(pvc.w) + bf2f(qvc.w) + mv.w, 0.f);
                }
                HT[(c0 + 0) * 72 + el] = f2bf(v0);
                HT[(c0 + 1) * 72 + el] = f2bf(v1);
                HT[(c0 + 2) * 72 + el] = f2bf(v2);
                HT[(c0 + 3) * 72 + el] = f2bf(v3);
            }
        }
        __syncthreads();

        // ---- phase 4: segment sum via MFMA: acc2 += S(32x64) @ hidden ----
        #pragma unroll
        for (int ks2 = 0; ks2 < 2; ks2++) {
            const u64 dv = dlocL[ks2 * 4 + (lane >> 4)];
            bf16x8 sfrag;
            #pragma unroll
            for (int j = 0; j < 8; j++) {
                const int dvj = (int)((dv >> (8 * j)) & 0xFF);
                sfrag[j] = (dvj == nodeid) ? (short)0x3F80 : (short)0;
            }
            #pragma unroll
            for (int i = 0; i < 4; i++) {
                const int col = (c2b + i) * 16 + (lane & 15);
                bf16x8 hfrag = *(const bf16x8*)(HT + col * 72 + ks2 * 32 + ((lane >> 4) << 3));
                acc2[i] = __builtin_amdgcn_mfma_f32_16x16x32_bf16(sfrag, hfrag, acc2[i], 0, 0, 0);
            }
        }
        __syncthreads();
        buf ^= 1;
    }

    u16* BNC = (u16*)XHT;
    #pragma unroll
    for (int i = 0; i < 4; i++) {
        const int col = (c2b + i) * 16 + (lane & 15);
        #pragma unroll
        for (int r = 0; r < 4; r++) {
            const int nl = rt * 16 + ((lane >> 4) << 2) + r;
            BNC[nl * 136 + col] = f2bf(acc2[i][r]);
        }
    }
    __syncthreads();
    for (int i = t; i < 32 * 16; i += 256) {
        const int row = i >> 4, c16 = i & 15;
        *(uint4*)(agg + (size_t)(n0 + row) * HD + c16 * 8) =
            *(const uint4*)(BNC + row * 136 + c16 * 8);
    }
}

// ---------------------------------------------------------------------------
// Batched weight folds + batched bias folds + wprep (R16 - measured good).
// ---------------------------------------------------------------------------
__global__ __launch_bounds__(256) void foldgemm_kernel(
    const float* __restrict__ ee_w2, const float* __restrict__ msg_w1,
    const float* __restrict__ msg_w2, const float* __restrict__ upd_w1,
    float* __restrict__ Mw, float* __restrict__ Mw2)
{
    __shared__ float Ws[HD * HD];
    __shared__ float Xs[32 * HD];
    const int m = blockIdx.x >> 2;
    const int l = m & 3;
    const float* X; const float* W; float* outp;
    if (m < 4) {
        X = ee_w2;
        W = msg_w1 + (size_t)l * 3 * HD2 + 2 * HD2;
        outp = Mw + (size_t)l * HD2;
    } else {
        X = msg_w2 + (size_t)l * HD2;
        W = upd_w1 + (size_t)l * 2 * HD2 + HD2;
        outp = Mw2 + (size_t)l * HD2;
    }
    const int t = threadIdx.x;
    for (int i = t; i < HD2 / 4; i += 256)
        ((float4*)Ws)[i] = ((const float4*)W)[i];
    const int c0 = (t & 31) * 4;
    const int rb = (t >> 5) * 4;
    const int r0 = (blockIdx.x & 3) * 32;
    for (int i = t; i < 32 * HD / 4; i += 256)
        ((float4*)Xs)[i] = ((const float4*)(X + (size_t)r0 * HD))[i];
    __syncthreads();
    float acc[4][4];
    #pragma unroll
    for (int a = 0; a < 4; a++)
        #pragma unroll
        for (int b = 0; b < 4; b++) acc[a][b] = 0.f;
    for (int k = 0; k < HD; k += 4) {
        float4 w0 = *(const float4*)(Ws + (k + 0) * HD + c0);
        float4 w1 = *(const float4*)(Ws + (k + 1) * HD + c0);
        float4 w2 = *(const float4*)(Ws + (k + 2) * HD + c0);
        float4 w3 = *(const float4*)(Ws + (k + 3) * HD + c0);
        #pragma unroll
        for (int rr = 0; rr < 4; rr++) {
            float4 xv = *(const float4*)(Xs + (rb + rr) * HD + k);
            acc[rr][0] += xv.x * w0.x + xv.y * w1.x + xv.z * w2.x + xv.w * w3.x;
            acc[rr][1] += xv.x * w0.y + xv.y * w1.y + xv.z * w2.y + xv.w * w3.y;
            acc[rr][2] += xv.x * w0.z + xv.y * w1.z + xv.z * w2.z + xv.w * w3.z;
            acc[rr][3] += xv.x * w0.w + xv.y * w1.w + xv.z * w2.w + xv.w * w3.w;
        }
    }
    #pragma unroll
    for (int rr = 0; rr < 4; rr++) {
        const int row = r0 + rb + rr;
        *(float4*)(outp + (size_t)row * HD + c0) =
            make_float4(acc[rr][0], acc[rr][1], acc[rr][2], acc[rr][3]);
    }
}

__global__ void mvecb_kernel(
    const float* __restrict__ ee_b2, const float* __restrict__ msg_w1,
    const float* __restrict__ msg_b1, const float* __restrict__ msg_b2,
    const float* __restrict__ upd_w1, float* __restrict__ mvec,
    float* __restrict__ b2u)
{
    const int m = blockIdx.x;
    const int l = m & 3;
    const int j = threadIdx.x;
    if (j >= HD) return;
    if (m < 4) {
        const float* W = msg_w1 + (size_t)l * 3 * HD2 + 2 * HD2;
        float s = msg_b1[(size_t)l * HD + j];
        for (int i = 0; i < HD; i++) s += ee_b2[i] * W[(size_t)i * HD + j];
        mvec[(size_t)l * HD + j] = s;
    } else {
        const float* W = upd_w1 + (size_t)l * 2 * HD2 + HD2;
        float s = 0.f;
        for (int i = 0; i < HD; i++) s += msg_b2[(size_t)l * HD + i] * W[(size_t)i * HD + j];
        b2u[(size_t)l * HD + j] = s;
    }
}

__global__ __launch_bounds__(256) void wprep_kernel(
    const float* __restrict__ msg_w1, const float* __restrict__ Mw2,
    const float* __restrict__ upd_w1, const float* __restrict__ upd_w2,
    const float* __restrict__ gw1, const float* __restrict__ ne_w2,
    const float* __restrict__ Mw, u16* __restrict__ wt)
{
    __shared__ float tileL[HD * (HD + 1)];
    const int b = blockIdx.x, t = threadIdx.x;
    const int l = b & 3;
    const float* S;
    if (b < 4)       S = msg_w1 + (size_t)l * 3 * HD2;
    else if (b < 8)  S = msg_w1 + (size_t)l * 3 * HD2 + HD2;
    else if (b < 12) S = Mw + (size_t)l * HD2;
    else if (b < 16) S = Mw2 + (size_t)l * HD2;
    else if (b < 20) S = upd_w1 + (size_t)l * 2 * HD2;
    else if (b < 24) S = upd_w1 + (size_t)l * 2 * HD2 + HD2;
    else if (b < 28) S = upd_w2 + (size_t)l * HD2;
    else if (b == 28) S = gw1;
    else             S = ne_w2;
    u16* D = wt + (size_t)b * HD2;
    for (int i = t; i < HD2; i += 256) {
        const int k = i >> 7, n = i & 127;
        tileL[k * (HD + 1) + n] = S[i];
    }
    __syncthreads();
    for (int i = t; i < HD2; i += 256) {
        const int n = i >> 7, k = i & 127;
        D[i] = f2bf(tileL[k * (HD + 1) + n]);
    }
}

// ---------------------------------------------------------------------------
// Node encoder layer 1 (7 -> 128), bf16 out.
// ---------------------------------------------------------------------------
__global__ __launch_bounds__(256) void ne1_kernel(
    const float* __restrict__ nf, const float* __restrict__ w1,
    const float* __restrict__ b1, u16* __restrict__ out)
{
    __shared__ float w1s[7 * HD];
    __shared__ float b1s[HD];
    const int t = threadIdx.x;
    for (int i = t; i < 7 * HD; i += 256) w1s[i] = w1[i];
    if (t < HD) b1s[t] = b1[t];
    __syncthreads();
    const int row = blockIdx.x * 32 + (t >> 3);
    const int c0 = (t & 7) * 16;
    if (row < NN) {
        float f[7];
        #pragma unroll
        for (int k = 0; k < 7; k++) f[k] = nf[(size_t)row * 7 + k];
        float o[16];
        #pragma unroll
        for (int c = 0; c < 16; c++) {
            float a = b1s[c0 + c];
            #pragma unroll
            for (int k = 0; k < 7; k++) a += f[k] * w1s[k * HD + c0 + c];
            o[c] = fmaxf(a, 0.f);
        }
        uint4 v0 = make_uint4(pk2(o[0], o[1]), pk2(o[2], o[3]), pk2(o[4], o[5]), pk2(o[6], o[7]));
        uint4 v1 = make_uint4(pk2(o[8], o[9]), pk2(o[10], o[11]), pk2(o[12], o[13]), pk2(o[14], o[15]));
        *(uint4*)(out + (size_t)row * HD + c0) = v0;
        *(uint4*)(out + (size_t)row * HD + c0 + 8) = v1;
    }
}

// ---------------------------------------------------------------------------
// CSR build.
// ---------------------------------------------------------------------------
__global__ void deg_count_kernel(const int* __restrict__ dst, int* __restrict__ deg) {
    const int i = blockIdx.x * 256 + threadIdx.x;
    if (i < NE) atomicAdd(&deg[dst[i]], 1);
}
__global__ void scan1_kernel(const int* __restrict__ deg, int* __restrict__ part) {
    __shared__ int s[256];
    const int t = threadIdx.x, i = blockIdx.x * 256 + t;
    s[t] = (i < NN) ? deg[i] : 0;
    __syncthreads();
    for (int d = 128; d > 0; d >>= 1) { if (t < d) s[t] += s[t + d]; __syncthreads(); }
    if (t == 0) part[blockIdx.x] = s[0];
}
__global__ void scan2_kernel(int* __restrict__ part, int nb) {
    if (threadIdx.x == 0 && blockIdx.x == 0) {
        int run = 0;
        for (int b = 0; b < nb; b++) { const int v = part[b]; part[b] = run; run += v; }
    }
}
__global__ void scan3_kernel(const int* __restrict__ deg, const int* __restrict__ part,
                             int* __restrict__ off, int* __restrict__ pos,
                             float* __restrict__ degf) {
    __shared__ int s[256];
    const int t = threadIdx.x, i = blockIdx.x * 256 + t;
    const int v = (i < NN) ? deg[i] : 0;
    s[t] = v;
    __syncthreads();
    for (int d = 1; d < 256; d <<= 1) {
        const int x = (t >= d) ? s[t - d] : 0;
        __syncthreads();
        s[t] += x;
        __syncthreads();
    }
    const int excl = s[t] - v + part[blockIdx.x];
    if (i < NN) {
        off[i] = excl; pos[i] = excl;
        degf[i] = (float)v;
        if (i == NN - 1) off[NN] = excl + v;
    }
}
__global__ void scatter_kernel(const int* __restrict__ src, const int* __restrict__ dst,
                               const float* __restrict__ ef, int* __restrict__ pos,
                               float2* __restrict__ sef, int* __restrict__ ssrc,
                               int* __restrict__ sdst) {
    const int e = blockIdx.x * 256 + threadIdx.x;
    if (e < NE) {
        const int d = dst[e];
        const int p = atomicAdd(&pos[d], 1);
        sef[p] = make_float2(ef[2 * e], ef[2 * e + 1]);
        ssrc[p] = src[e]; sdst[p] = d;
    }
}

__global__ void bounds_kernel(const int* __restrict__ gid, int* __restrict__ gs) {
    const int g = threadIdx.x;
    if (g <= NG) {
        int lo = 0, hi = NN;
        while (lo < hi) {
            const int mid = (lo + hi) >> 1;
            if (gid[mid] < g) lo = mid + 1; else hi = mid;
        }
        gs[g] = lo;
    }
}

// ---------------------------------------------------------------------------
// Pooling (3-stage) + policy head (measured good).
// ---------------------------------------------------------------------------
__global__ __launch_bounds__(256) void poolA_kernel(
    const float* __restrict__ gate, const int* __restrict__ gs,
    float* __restrict__ ex, float* __restrict__ gz)
{
    __shared__ float red[256];
    const int g = blockIdx.x, t = threadIdx.x;
    const int s = gs[g], e = gs[g + 1];
    if (s >= e) {
        if (t == 0) gz[g] = 1.f;
        return;
    }
    float m = -3.4e38f;
    for (int i = s + t; i < e; i += 256) m = fmaxf(m, gate[i]);
    red[t] = m; __syncthreads();
    for (int d = 128; d > 0; d >>= 1) {
        if (t < d) red[t] = fmaxf(red[t], red[t + d]);
        __syncthreads();
    }
    const float gm = red[0];
    __syncthreads();
    float zs = 0.f;
    for (int i = s + t; i < e; i += 256) {
        const float ev = expf(gate[i] - gm);
        ex[i] = ev; zs += ev;
    }
    red[t] = zs; __syncthreads();
    for (int d = 128; d > 0; d >>= 1) {
        if (t < d) red[t] += red[t + d];
        __syncthreads();
    }
    if (t == 0) gz[g] = red[0];
}

__global__ __launch_bounds__(256) void poolB_kernel(
    const float* __restrict__ ex, const int* __restrict__ gs,
    const u16* __restrict__ hb, float* __restrict__ partial)
{
    __shared__ float redL[16][132];
    const int b = blockIdx.x;
    const int g = b / PSLICE, sl = b % PSLICE;
    const int lo = gs[g], hi = gs[g + 1];
    const int len = hi - lo;
    const int chunk = (len + PSLICE - 1) / PSLICE;
    const int ns = lo + sl * chunk;
    const int ne = min(ns + chunk, hi);
    const int t = threadIdx.x;
    const int c8 = (t & 15) * 8;
    const int ro = t >> 4;
    float acc[8] = {0.f, 0.f, 0.f, 0.f, 0.f, 0.f, 0.f, 0.f};
    for (int n = ns + ro; n < ne; n += 16) {
        const float w = ex[n];
        const ushort4 h0 = *(const ushort4*)(hb + (size_t)n * HD + c8);
        const ushort4 h1 = *(const ushort4*)(hb + (size_t)n * HD + c8 + 4);
        acc[0] += w * bf2f(h0.x); acc[1] += w * bf2f(h0.y);
        acc[2] += w * bf2f(h0.z); acc[3] += w * bf2f(h0.w);
        acc[4] += w * bf2f(h1.x); acc[5] += w * bf2f(h1.y);
        acc[6] += w * bf2f(h1.z); acc[7] += w * bf2f(h1.w);
    }
    #pragma unroll
    for (int j = 0; j < 8; j++) redL[ro][c8 + j] = acc[j];
    __syncthreads();
    if (t < HD) {
        float s = 0.f;
        #pragma unroll
        for (int r = 0; r < 16; r++) s += redL[r][t];
        partial[(size_t)b * HD + t] = s;
    }
}

__global__ void poolC_kernel(const float* __restrict__ partial,
                             const float* __restrict__ gz,
                             float* __restrict__ emb)
{
    const int g = blockIdx.x, t = threadIdx.x;
    float s = 0.f;
    #pragma unroll
    for (int sl = 0; sl < PSLICE; sl++)
        s += partial[(size_t)(g * PSLICE + sl) * HD + t];
    emb[(size_t)g * HD + t] = s / gz[g];
}

__global__ __launch_bounds__(256) void policy_kernel(
    const float* __restrict__ emb,
    const float* __restrict__ w1, const float* __restrict__ b1,
    const float* __restrict__ w2, const float* __restrict__ b2,
    const float* __restrict__ w3, const float* __restrict__ b3,
    float* __restrict__ out)
{
    __shared__ float A[NG * HD];
    __shared__ float Bs[NG * HD];
    const int t = threadIdx.x;
    for (int i = t; i < NG * HD / 4; i += 256)
        ((float4*)A)[i] = ((const float4*)emb)[i];
    __syncthreads();
    const int c0 = (t & 31) * 4;
    const int rb = (t >> 5) * 8;
    {
        float4 bv = *(const float4*)(b1 + c0);
        for (int rr = 0; rr < 8; rr++) {
            const int r = rb + rr;
            float a0 = bv.x, a1 = bv.y, a2 = bv.z, a3 = bv.w;
            for (int k = 0; k < HD; k++) {
                const float x = A[r * HD + k];
                float4 wv = *(const float4*)(w1 + k * HD + c0);
                a0 += x * wv.x; a1 += x * wv.y; a2 += x * wv.z; a3 += x * wv.w;
            }
            *(float4*)(Bs + r * HD + c0) =
                make_float4(fmaxf(a0, 0.f), fmaxf(a1, 0.f), fmaxf(a2, 0.f), fmaxf(a3, 0.f));
        }
    }
    __syncthreads();
    {
        float4 bv = *(const float4*)(b2 + c0);
        for (int rr = 0; rr < 8; rr++) {
            const int r = rb + rr;
            float a0 = bv.x, a1 = bv.y, a2 = bv.z, a3 = bv.w;
            for (int k = 0; k < HD; k++) {
                const float x = Bs[r * HD + k];
                float4 wv = *(const float4*)(w2 + k * HD + c0);
                a0 += x * wv.x; a1 += x * wv.y; a2 += x * wv.z; a3 += x * wv.w;
            }
            *(float4*)(A + r * HD + c0) =
                make_float4(fmaxf(a0, 0.f), fmaxf(a1, 0.f), fmaxf(a2, 0.f), fmaxf(a3, 0.f));
        }
    }
    __syncthreads();
    {
        float4 bv = *(const float4*)(b3 + c0);
        for (int rr = 0; rr < 8; rr++) {
            const int r = rb + rr;
            float a[4] = {bv.x, bv.y, bv.z, bv.w};
            for (int k = 0; k < HD; k++) {
                const float x = A[r * HD + k];
                float4 wv = *(const float4*)(w3 + k * HD + c0);
                a[0] += x * wv.x; a[1] += x * wv.y; a[2] += x * wv.z; a[3] += x * wv.w;
            }
            #pragma unroll
            for (int j = 0; j < 4; j++) {
                const int c = c0 + j;
                if (c < 64) {
                    out[r * 64 + c] = a[j];
                } else {
                    const float ls = fminf(fmaxf(a[j], -20.f), 2.f);
                    out[4096 + r * 64 + (c - 64)] = expf(ls);
                }
            }
        }
    }
}

// ---------------------------------------------------------------------------
extern "C" void kernel_launch(void* const* d_in, const int* in_sizes, int n_in,
                              void* d_out, int out_size, void* d_ws, size_t ws_size,
                              hipStream_t stream) {
    const float* node_feat = (const float*)d_in[0];
    const float* edge_feat = (const float*)d_in[1];
    const float* ne_w1 = (const float*)d_in[2];
    const float* ne_b1 = (const float*)d_in[3];
    const float* ne_w2 = (const float*)d_in[4];
    const float* ne_b2 = (const float*)d_in[5];
    const float* ee_w1 = (const float*)d_in[6];
    const float* ee_b1 = (const float*)d_in[7];
    const float* ee_w2 = (const float*)d_in[8];
    const float* ee_b2 = (const float*)d_in[9];
    const float* msg_w1 = (const float*)d_in[10];
    const float* msg_b1 = (const float*)d_in[11];
    const float* msg_w2 = (const float*)d_in[12];
    const float* msg_b2 = (const float*)d_in[13];
    const float* upd_w1 = (const float*)d_in[14];
    const float* upd_b1 = (const float*)d_in[15];
    const float* upd_w2 = (const float*)d_in[16];
    const float* upd_b2 = (const float*)d_in[17];
    const float* gate_w1 = (const float*)d_in[18];
    const float* gate_b1 = (const float*)d_in[19];
    const float* gate_w2 = (const float*)d_in[20];
    const float* gate_b2 = (const float*)d_in[21];
    const float* pol_w1 = (const float*)d_in[22];
    const float* pol_b1 = (const float*)d_in[23];
    const float* pol_w2 = (const float*)d_in[24];
    const float* pol_b2 = (const float*)d_in[25];
    const float* pol_w3 = (const float*)d_in[26];
    const float* pol_b3 = (const float*)d_in[27];
    const int* src = (const int*)d_in[28];
    const int* dst = (const int*)d_in[29];
    const int* gid = (const int*)d_in[30];

    // ---- workspace layout (~143 MB) ----
    char* p = (char*)d_ws;
    u16* hb   = (u16*)p;    p += (size_t)NN * HD * 2;
    u16* Pb   = (u16*)p;    p += (size_t)NN * HD * 2;
    u16* Qb   = (u16*)p;    p += (size_t)NN * HD * 2;
    u16* aggb = (u16*)p;    p += (size_t)NN * HD * 2;
    u16* tub  = (u16*)p;    p += (size_t)NN * HD * 2;
    float2* sef = (float2*)p; p += (size_t)NE * 8;
    int* ssrc = (int*)p;    p += (size_t)NE * 4;
    int* sdst = (int*)p;    p += (size_t)NE * 4;
    int* off  = (int*)p;    p += (size_t)(NN + 4) * 4;
    int* pos  = (int*)p;    p += (size_t)NN * 4;
    int* deg  = (int*)p;    p += (size_t)NN * 4;
    float* degf = (float*)p; p += (size_t)NN * 4;
    float* gate = (float*)p; p += (size_t)NN * 4;
    float* ex   = (float*)p; p += (size_t)NN * 4;
    int* part = (int*)p;    p += 2048;
    int* gs   = (int*)p;    p += 512;
    float* gz   = (float*)p; p += 256;
    float* emb = (float*)p; p += (size_t)NG * HD * 4;
    float* partialP = (float*)p; p += (size_t)NG * PSLICE * HD * 4;
    float* Mw  = (float*)p; p += (size_t)NLAYER * HD2 * 4;
    float* Mw2 = (float*)p; p += (size_t)NLAYER * HD2 * 4;
    float* mvec = (float*)p; p += (size_t)NLAYER * HD * 4;
    float* b2u  = (float*)p; p += (size_t)NLAYER * HD * 4;
    u16* wt = (u16*)p;      p += (size_t)30 * HD2 * 2;

    // ---- CSR build ----
    hipMemsetAsync(deg, 0, (size_t)NN * 4, stream);
    deg_count_kernel<<<(NE + 255) / 256, 256, 0, stream>>>(dst, deg);
    scan1_kernel<<<SCAN_NB, 256, 0, stream>>>(deg, part);
    scan2_kernel<<<1, 64, 0, stream>>>(part, SCAN_NB);
    scan3_kernel<<<SCAN_NB, 256, 0, stream>>>(deg, part, off, pos, degf);
    scatter_kernel<<<(NE + 255) / 256, 256, 0, stream>>>(src, dst, edge_feat, pos, sef, ssrc, sdst);
    bounds_kernel<<<1, 128, 0, stream>>>(gid, gs);

    // ---- weight folds (batched) + prep ----
    foldgemm_kernel<<<32, 256, 0, stream>>>(ee_w2, msg_w1, msg_w2, upd_w1, Mw, Mw2);
    mvecb_kernel<<<8, 128, 0, stream>>>(ee_b2, msg_w1, msg_b1, msg_b2, upd_w1, mvec, b2u);
    wprep_kernel<<<30, 256, 0, stream>>>(msg_w1, Mw2, upd_w1, upd_w2, gate_w1, ne_w2, Mw, wt);

    // ---- node encoder ----
    ne1_kernel<<<3125, 256, 0, stream>>>(node_feat, ne_w1, ne_b1, Pb);
    mgemm_kernel<false, false><<<512, 256, 0, stream>>>(
        Pb, wt + (size_t)29 * HD2, ne_b2, nullptr, nullptr, hb, NN, nullptr, nullptr, nullptr);

    // ---- message-passing layers (4 dispatches/layer, R16 structure) ----
    for (int l = 0; l < NLAYER; l++) {
        pqtgemm_kernel<<<512, 256, 0, stream>>>(
            hb, wt + (size_t)(0 + l) * HD2, wt + (size_t)(4 + l) * HD2,
            wt + (size_t)(16 + l) * HD2, upd_b1 + (size_t)l * HD, Pb, Qb, tub, NN);
        edge_mfma_kernel<<<NN / 32, 256, 0, stream>>>(sef, ssrc, sdst, off, ee_w1, ee_b1,
            wt + (size_t)(8 + l) * HD2, mvec + (size_t)l * HD, Pb, Qb, aggb);
        mgemm_kernel<true, false><<<512, 256, 0, stream>>>(
            aggb, wt + (size_t)(12 + l) * HD2, b2u + (size_t)l * HD, degf, tub, Pb, NN,
            nullptr, nullptr, nullptr);
        mgemm_kernel<false, false><<<512, 256, 0, stream>>>(
            Pb, wt + (size_t)(24 + l) * HD2, upd_b2 + (size_t)l * HD, nullptr, hb, hb, NN,
            nullptr, nullptr, nullptr);
    }

    // ---- gate (fused dot) + pooling (3-stage) + policy ----
    mgemm_kernel<true, true><<<512, 256, 0, stream>>>(
        hb, wt + (size_t)28 * HD2, gate_b1, nullptr, nullptr, nullptr, NN,
        gate_w2, gate_b2, gate);
    poolA_kernel<<<NG, 256, 0, stream>>>(gate, gs, ex, gz);
    poolB_kernel<<<NG * PSLICE, 256, 0, stream>>>(ex, gs, hb, partialP);
    poolC_kernel<<<NG, 128, 0, stream>>>(partialP, gz, emb);
    policy_kernel<<<1, 256, 0, stream>>>(emb, pol_w1, pol_b1, pol_w2, pol_b2, pol_w3, pol_b3, (float*)d_out);
}

// Round 21
// 1297.543 us; speedup vs baseline: 1.2363x; 1.1724x over previous
//
#include <hip/hip_runtime.h>
#include <stdint.h>

#define NN 100000
#define NE 600000
#define NG 64
#define HD 128
#define HD2 (HD*HD)
#define NLAYER 4
#define SCAN_NB 391   // ceil(NN/256)
#define NTILES ((NN + 63) / 64)
#define PSLICE 16

typedef unsigned short u16;
typedef unsigned int u32;
typedef unsigned long long u64;
typedef __attribute__((ext_vector_type(8))) short bf16x8;   // 8 bf16 = 4 VGPR
typedef __attribute__((ext_vector_type(4))) float f32x4;

__device__ __forceinline__ float bf2f(u32 v) { return __uint_as_float(v << 16); }
__device__ __forceinline__ u16 f2bf(float f) {
    u32 u = __float_as_uint(f);
    return (u16)((u + 0x7FFFu + ((u >> 16) & 1u)) >> 16);
}
__device__ __forceinline__ u32 pk2(float a, float b) {
    return (u32)f2bf(a) | ((u32)f2bf(b) << 16);
}

// ---------------------------------------------------------------------------
// MFMA GEMM (measured good - unchanged, grid 512).
// ---------------------------------------------------------------------------
template<bool RELU, bool GATE>
__global__ __launch_bounds__(256, 3) void mgemm_kernel(
    const u16* __restrict__ Xb, const u16* __restrict__ Wt,
    const float* __restrict__ bias, const float* __restrict__ degscale,
    const u16* __restrict__ addend, u16* __restrict__ out, int M,
    const float* __restrict__ gw2, const float* __restrict__ gb2,
    float* __restrict__ gate)
{
    __shared__ u16 WsL[HD * HD];   // 32 KB swizzled weights
    __shared__ u16 XsL[64 * HD];   // 16 KB swizzled X tile
    const int t = threadIdx.x;
    const int lane = t & 63, wave = t >> 6;
    const int cj = ((lane >> 4) << 2);

    for (int i = t; i < HD * 16; i += 256) {
        const int row = i >> 4, c16 = i & 15;
        uint4 v = *(const uint4*)(Wt + (size_t)row * HD + c16 * 8);
        *(uint4*)((char*)WsL + (((row << 8) + (c16 << 4)) ^ ((row & 7) << 4))) = v;
    }
    float4 bcol[8];
    #pragma unroll
    for (int ct = 0; ct < 8; ct++)
        bcol[ct] = bias ? *(const float4*)(bias + ct * 16 + cj)
                        : make_float4(0.f, 0.f, 0.f, 0.f);
    float4 gwv[8];
    if (GATE) {
        #pragma unroll
        for (int ct = 0; ct < 8; ct++)
            gwv[ct] = *(const float4*)(gw2 + ct * 16 + cj);
    }

    const int arow = wave * 16 + (lane & 15);
    const int alin = (arow << 8) + ((lane >> 4) << 4);
    const int axor = (arow & 7) << 4;
    __syncthreads();

    for (int tile = blockIdx.x; tile < NTILES; tile += gridDim.x) {
        const int r0 = tile << 6;
        for (int i = t; i < 64 * 16; i += 256) {
            const int row = i >> 4, c16 = i & 15;
            const int rg = r0 + row;
            uint4 v = make_uint4(0, 0, 0, 0);
            if (rg < M) v = *(const uint4*)(Xb + (size_t)rg * HD + c16 * 8);
            *(uint4*)((char*)XsL + (((row << 8) + (c16 << 4)) ^ ((row & 7) << 4))) = v;
        }
        __syncthreads();

        bf16x8 a[4];
        #pragma unroll
        for (int ks = 0; ks < 4; ks++)
            a[ks] = *(const bf16x8*)((const char*)XsL + ((alin + ks * 64) ^ axor));

        f32x4 acc[8];
        #pragma unroll
        for (int ct = 0; ct < 8; ct++) {
            acc[ct][0] = 0.f; acc[ct][1] = 0.f; acc[ct][2] = 0.f; acc[ct][3] = 0.f;
        }
        #pragma unroll
        for (int ct = 0; ct < 8; ct++) {
            const int bn = ct * 16 + (lane & 15);
            #pragma unroll
            for (int ks = 0; ks < 4; ks++) {
                bf16x8 breg = *(const bf16x8*)((const char*)WsL +
                    (((bn << 8) + ks * 64 + ((lane >> 4) << 4)) ^ ((bn & 7) << 4)));
                acc[ct] = __builtin_amdgcn_mfma_f32_16x16x32_bf16(breg, a[ks], acc[ct], 0, 0, 0);
            }
        }

        const int orow = r0 + wave * 16 + (lane & 15);
        const bool rv = orow < M;
        float gdot = 0.f;
        const float ds = (degscale && rv) ? degscale[orow] : 1.f;
        #pragma unroll
        for (int ct = 0; ct < 8; ct++) {
            const int c0 = ct * 16 + cj;
            float v0 = acc[ct][0], v1 = acc[ct][1], v2 = acc[ct][2], v3 = acc[ct][3];
            if (bias) {
                v0 += bcol[ct].x * ds; v1 += bcol[ct].y * ds;
                v2 += bcol[ct].z * ds; v3 += bcol[ct].w * ds;
            }
            if (addend && rv) {
                ushort4 av = *(const ushort4*)(addend + (size_t)orow * HD + c0);
                v0 += bf2f(av.x); v1 += bf2f(av.y); v2 += bf2f(av.z); v3 += bf2f(av.w);
            }
            if (RELU) {
                v0 = fmaxf(v0, 0.f); v1 = fmaxf(v1, 0.f);
                v2 = fmaxf(v2, 0.f); v3 = fmaxf(v3, 0.f);
            }
            if (GATE) {
                gdot += v0 * gwv[ct].x + v1 * gwv[ct].y + v2 * gwv[ct].z + v3 * gwv[ct].w;
            } else if (rv) {
                ushort4 pk;
                pk.x = f2bf(v0); pk.y = f2bf(v1); pk.z = f2bf(v2); pk.w = f2bf(v3);
                *(ushort4*)(out + (size_t)orow * HD + c0) = pk;
            }
        }
        if (GATE) {
            gdot += __shfl_xor(gdot, 16, 64);
            gdot += __shfl_xor(gdot, 32, 64);
            if ((lane >> 4) == 0 && rv) gate[orow] = gdot + gb2[0];
        }
        __syncthreads();
    }
}

// ---------------------------------------------------------------------------
// Triple-output GEMM (R15 - measured good).
// ---------------------------------------------------------------------------
__global__ __launch_bounds__(256, 2) void pqtgemm_kernel(
    const u16* __restrict__ Xb, const u16* __restrict__ WtP,
    const u16* __restrict__ WtQ, const u16* __restrict__ WtT,
    const float* __restrict__ tb, u16* __restrict__ outP,
    u16* __restrict__ outQ, u16* __restrict__ outT, int M)
{
    __shared__ u16 WsL[2 * HD * HD];   // 64 KB swizzled weights (P|Q)
    __shared__ u16 XsL[64 * HD];       // 16 KB swizzled X tile
    const int t = threadIdx.x;
    const int lane = t & 63, wave = t >> 6;
    const int cj = ((lane >> 4) << 2);

    for (int i = t; i < 2 * HD * 16; i += 256) {
        const int w = i >> 11;               // HD*16 = 2048
        const int j = i & 2047;
        const int row = j >> 4, c16 = j & 15;
        const u16* Wt = w ? WtQ : WtP;
        uint4 v = *(const uint4*)(Wt + (size_t)row * HD + c16 * 8);
        *(uint4*)((char*)WsL + w * 32768 +
                  (((row << 8) + (c16 << 4)) ^ ((row & 7) << 4))) = v;
    }
    bf16x8 treg[8][4];
    #pragma unroll
    for (int ct = 0; ct < 8; ct++) {
        const int bn = ct * 16 + (lane & 15);
        #pragma unroll
        for (int ks = 0; ks < 4; ks++)
            treg[ct][ks] = *(const bf16x8*)(WtT + (size_t)bn * HD + ks * 32 + ((lane >> 4) << 3));
    }
    float4 tbc[8];
    #pragma unroll
    for (int ct = 0; ct < 8; ct++)
        tbc[ct] = *(const float4*)(tb + ct * 16 + cj);

    const int arow = wave * 16 + (lane & 15);
    const int alin = (arow << 8) + ((lane >> 4) << 4);
    const int axor = (arow & 7) << 4;
    __syncthreads();

    for (int tile = blockIdx.x; tile < NTILES; tile += gridDim.x) {
        const int r0 = tile << 6;
        for (int i = t; i < 64 * 16; i += 256) {
            const int row = i >> 4, c16 = i & 15;
            const int rg = r0 + row;
            uint4 v = make_uint4(0, 0, 0, 0);
            if (rg < M) v = *(const uint4*)(Xb + (size_t)rg * HD + c16 * 8);
            *(uint4*)((char*)XsL + (((row << 8) + (c16 << 4)) ^ ((row & 7) << 4))) = v;
        }
        __syncthreads();

        bf16x8 a[4];
        #pragma unroll
        for (int ks = 0; ks < 4; ks++)
            a[ks] = *(const bf16x8*)((const char*)XsL + ((alin + ks * 64) ^ axor));

        const int orow = r0 + wave * 16 + (lane & 15);
        const bool rv = orow < M;

        #pragma unroll
        for (int o = 0; o < 2; o++) {
            f32x4 acc[8];
            #pragma unroll
            for (int ct = 0; ct < 8; ct++) {
                acc[ct][0] = 0.f; acc[ct][1] = 0.f; acc[ct][2] = 0.f; acc[ct][3] = 0.f;
            }
            #pragma unroll
            for (int ct = 0; ct < 8; ct++) {
                const int bn = ct * 16 + (lane & 15);
                #pragma unroll
                for (int ks = 0; ks < 4; ks++) {
                    bf16x8 breg = *(const bf16x8*)((const char*)WsL + o * 32768 +
                        (((bn << 8) + ks * 64 + ((lane >> 4) << 4)) ^ ((bn & 7) << 4)));
                    acc[ct] = __builtin_amdgcn_mfma_f32_16x16x32_bf16(breg, a[ks], acc[ct], 0, 0, 0);
                }
            }
            if (rv) {
                u16* out = o ? outQ : outP;
                #pragma unroll
                for (int ct = 0; ct < 8; ct++) {
                    ushort4 pk;
                    pk.x = f2bf(acc[ct][0]); pk.y = f2bf(acc[ct][1]);
                    pk.z = f2bf(acc[ct][2]); pk.w = f2bf(acc[ct][3]);
                    *(ushort4*)(out + (size_t)orow * HD + ct * 16 + cj) = pk;
                }
            }
        }
        {
            f32x4 acc[8];
            #pragma unroll
            for (int ct = 0; ct < 8; ct++) {
                acc[ct][0] = 0.f; acc[ct][1] = 0.f; acc[ct][2] = 0.f; acc[ct][3] = 0.f;
            }
            #pragma unroll
            for (int ct = 0; ct < 8; ct++)
                #pragma unroll
                for (int ks = 0; ks < 4; ks++)
                    acc[ct] = __builtin_amdgcn_mfma_f32_16x16x32_bf16(treg[ct][ks], a[ks], acc[ct], 0, 0, 0);
            if (rv) {
                #pragma unroll
                for (int ct = 0; ct < 8; ct++) {
                    ushort4 pk;
                    pk.x = f2bf(acc[ct][0] + tbc[ct].x);
                    pk.y = f2bf(acc[ct][1] + tbc[ct].y);
                    pk.z = f2bf(acc[ct][2] + tbc[ct].z);
                    pk.w = f2bf(acc[ct][3] + tbc[ct].w);
                    *(ushort4*)(outT + (size_t)orow * HD + ct * 16 + cj) = pk;
                }
            }
        }
        __syncthreads();
    }
}

// ---------------------------------------------------------------------------
// Edge message pass (R18 - best measured: 167.5us, clean counters).
// 2 blocks/CU is the structural optimum: live set ~176 regs > 170.7
// threshold for 3 waves/SIMD; all attempts to cross it spill (R19/R20).
// ---------------------------------------------------------------------------
__global__ __launch_bounds__(256, 2) void edge_mfma_kernel(
    const float2* __restrict__ sef, const int* __restrict__ ssrc,
    const int* __restrict__ sdst, const int* __restrict__ off,
    const float* __restrict__ ew1, const float* __restrict__ eb1,
    const u16* __restrict__ Mt, const float* __restrict__ mvec,
    const u16* __restrict__ P, const u16* __restrict__ Q,
    u16* __restrict__ agg)
{
    __shared__ __align__(16) char XHT[HD * 72 * 2];   // 18 KB: XsL | HT | BNC
    __shared__ u16 PsL[64 * 136];    // 17 KB staged P rows
    __shared__ u16 QsL[32 * 136];    // 8.5 KB staged Q rows
    __shared__ u64 dlocL[8];         // 64 x u8 local-dst per tile
    __shared__ int nsrcL[2][64];     // 512 B double-buffered ssrc prefetch
    __shared__ float ew1L[2 * HD];
    __shared__ float eb1L[HD];
    __shared__ float mvL[HD];        // 512 B mvec
    u16* HT = (u16*)XHT;
    const int t = threadIdx.x, lane = t & 63, wave = t >> 6;
    const int cj = (lane >> 4) << 2;
    const int n0 = blockIdx.x * 32;

    ew1L[t] = ew1[t];
    if (t < HD) { eb1L[t] = eb1[t]; mvL[t] = mvec[t]; }
    for (int i = t; i < 32 * 32; i += 256) {
        const int row = i >> 5, c4 = (i & 31) * 4;
        *(ushort4*)(QsL + row * 136 + c4) = *(const ushort4*)(Q + (size_t)(n0 + row) * HD + c4);
    }

    bf16x8 breg[8][4];
    #pragma unroll
    for (int ct = 0; ct < 8; ct++) {
        const int bn = ct * 16 + (lane & 15);
        #pragma unroll
        for (int ks = 0; ks < 4; ks++)
            breg[ct][ks] = *(const bf16x8*)(Mt + (size_t)bn * HD + ks * 32 + ((lane >> 4) << 3));
    }

    const int rt = wave & 1;
    const int c2b = (wave >> 1) * 4;
    const int nodeid = rt * 16 + (lane & 15);
    f32x4 acc2[4];
    #pragma unroll
    for (int i = 0; i < 4; i++) {
        acc2[i][0] = 0.f; acc2[i][1] = 0.f; acc2[i][2] = 0.f; acc2[i][3] = 0.f;
    }

    const int e0 = off[n0], e1 = off[n0 + 32];
    const int arow = wave * 16 + (lane & 15);
    const int alin = (arow << 8) + ((lane >> 4) << 4);
    const int axor = (arow & 7) << 4;
    const int el = wave * 16 + (lane & 15);
    if (t < 64) nsrcL[0][t] = (e0 + t < e1) ? ssrc[e0 + t] : 0;
    __syncthreads();

    int buf = 0;
    for (int base = e0; base < e1; base += 64) {
        for (int i = t; i < 64 * 16; i += 256) {
            const int row = i >> 4, c16 = i & 15;
            const int e = base + row;
            uint4 v = make_uint4(0, 0, 0, 0);
            uint4 pvv = make_uint4(0, 0, 0, 0);
            if (e < e1) {
                const float2 f = sef[e];
                const int c8 = c16 * 8;
                float o[8];
                #pragma unroll
                for (int k = 0; k < 8; k++)
                    o[k] = fmaxf(f.x * ew1L[c8 + k] + f.y * ew1L[HD + c8 + k] + eb1L[c8 + k], 0.f);
                v = make_uint4(pk2(o[0], o[1]), pk2(o[2], o[3]), pk2(o[4], o[5]), pk2(o[6], o[7]));
                const int srcI = nsrcL[buf][row];
                pvv = *(const uint4*)(P + (size_t)srcI * HD + c16 * 8);
            }
            *(uint4*)(XHT + (((row << 8) + (c16 << 4)) ^ ((row & 7) << 4))) = v;
            *(uint4*)(PsL + row * 136 + c16 * 8) = pvv;
        }
        if (t < 64) {
            const int e = base + t;
            ((unsigned char*)dlocL)[t] = (e < e1) ? (unsigned char)(sdst[e] - n0) : (unsigned char)0xFF;
            const int e2 = base + 64 + t;
            nsrcL[buf ^ 1][t] = (e2 < e1) ? ssrc[e2] : 0;
        }
        __syncthreads();

        bf16x8 a[4];
        #pragma unroll
        for (int ks = 0; ks < 4; ks++)
            a[ks] = *(const bf16x8*)(XHT + ((alin + ks * 64) ^ axor));
        const int e = base + el;
        const bool ev = e < e1;
        const int dl = ev ? (int)((const unsigned char*)dlocL)[el] : 0;
        __syncthreads();   // all XsL reads done before HT overwrite

        f32x4 acc[8];
        #pragma unroll
        for (int ct = 0; ct < 8; ct++) {
            acc[ct][0] = 0.f; acc[ct][1] = 0.f; acc[ct][2] = 0.f; acc[ct][3] = 0.f;
        }
        #pragma unroll
        for (int ct = 0; ct < 8; ct++)
            #pragma unroll
            for (int ks = 0; ks < 4; ks++)
                acc[ct] = __builtin_amdgcn_mfma_f32_16x16x32_bf16(breg[ct][ks], a[ks], acc[ct], 0, 0, 0);

        #pragma unroll
        for (int ct = 0; ct < 8; ct++) {
            const int c0 = ct * 16 + cj;
            float v0 = 0.f, v1 = 0.f, v2 = 0.f, v3 = 0.f;
            if (ev) {
                const ushort4 pvc = *(const ushort4*)(PsL + el * 136 + c0);
                const ushort4 qvc = *(const ushort4*)(QsL + dl * 136 + c0);
                const float4 mv = *(const float4*)(mvL + c0);
                v0 = fmaxf(acc[ct][0] + bf2f(pvc.x) + bf2f(qvc.x) + mv.x, 0.f);
                v1 = fmaxf(acc[ct][1] + bf2f(pvc.y) + bf2f(qvc.y) + mv.y, 0.f);
                v2 = fmaxf(acc[ct][2] + bf2f(pvc.z) + bf2f(qvc.z) + mv.z, 0.f);
                v3 = fmaxf(acc[ct][3] + bf2f(pvc.w) + bf2f(qvc.w) + mv.w, 0.f);
            }
            HT[(c0 + 0) * 72 + el] = f2bf(v0);
            HT[(c0 + 1) * 72 + el] = f2bf(v1);
            HT[(c0 + 2) * 72 + el] = f2bf(v2);
            HT[(c0 + 3) * 72 + el] = f2bf(v3);
        }
        __syncthreads();

        #pragma unroll
        for (int ks2 = 0; ks2 < 2; ks2++) {
            const u64 dv = dlocL[ks2 * 4 + (lane >> 4)];
            bf16x8 sfrag;
            #pragma unroll
            for (int j = 0; j < 8; j++) {
                const int dvj = (int)((dv >> (8 * j)) & 0xFF);
                sfrag[j] = (dvj == nodeid) ? (short)0x3F80 : (short)0;
            }
            #pragma unroll
            for (int i = 0; i < 4; i++) {
                const int col = (c2b + i) * 16 + (lane & 15);
                bf16x8 hfrag = *(const bf16x8*)(HT + col * 72 + ks2 * 32 + ((lane >> 4) << 3));
                acc2[i] = __builtin_amdgcn_mfma_f32_16x16x32_bf16(sfrag, hfrag, acc2[i], 0, 0, 0);
            }
        }
        __syncthreads();
        buf ^= 1;
    }

    u16* BNC = (u16*)XHT;
    #pragma unroll
    for (int i = 0; i < 4; i++) {
        const int col = (c2b + i) * 16 + (lane & 15);
        #pragma unroll
        for (int r = 0; r < 4; r++) {
            const int nl = rt * 16 + ((lane >> 4) << 2) + r;
            BNC[nl * 136 + col] = f2bf(acc2[i][r]);
        }
    }
    __syncthreads();
    for (int i = t; i < 32 * 16; i += 256) {
        const int row = i >> 4, c16 = i & 15;
        *(uint4*)(agg + (size_t)(n0 + row) * HD + c16 * 8) =
            *(const uint4*)(BNC + row * 136 + c16 * 8);
    }
}

// ---------------------------------------------------------------------------
// Batched weight folds + batched bias folds + wprep (R16 - measured good).
// ---------------------------------------------------------------------------
__global__ __launch_bounds__(256) void foldgemm_kernel(
    const float* __restrict__ ee_w2, const float* __restrict__ msg_w1,
    const float* __restrict__ msg_w2, const float* __restrict__ upd_w1,
    float* __restrict__ Mw, float* __restrict__ Mw2)
{
    __shared__ float Ws[HD * HD];
    __shared__ float Xs[32 * HD];
    const int m = blockIdx.x >> 2;
    const int l = m & 3;
    const float* X; const float* W; float* outp;
    if (m < 4) {
        X = ee_w2;
        W = msg_w1 + (size_t)l * 3 * HD2 + 2 * HD2;
        outp = Mw + (size_t)l * HD2;
    } else {
        X = msg_w2 + (size_t)l * HD2;
        W = upd_w1 + (size_t)l * 2 * HD2 + HD2;
        outp = Mw2 + (size_t)l * HD2;
    }
    const int t = threadIdx.x;
    for (int i = t; i < HD2 / 4; i += 256)
        ((float4*)Ws)[i] = ((const float4*)W)[i];
    const int c0 = (t & 31) * 4;
    const int rb = (t >> 5) * 4;
    const int r0 = (blockIdx.x & 3) * 32;
    for (int i = t; i < 32 * HD / 4; i += 256)
        ((float4*)Xs)[i] = ((const float4*)(X + (size_t)r0 * HD))[i];
    __syncthreads();
    float acc[4][4];
    #pragma unroll
    for (int a = 0; a < 4; a++)
        #pragma unroll
        for (int b = 0; b < 4; b++) acc[a][b] = 0.f;
    for (int k = 0; k < HD; k += 4) {
        float4 w0 = *(const float4*)(Ws + (k + 0) * HD + c0);
        float4 w1 = *(const float4*)(Ws + (k + 1) * HD + c0);
        float4 w2 = *(const float4*)(Ws + (k + 2) * HD + c0);
        float4 w3 = *(const float4*)(Ws + (k + 3) * HD + c0);
        #pragma unroll
        for (int rr = 0; rr < 4; rr++) {
            float4 xv = *(const float4*)(Xs + (rb + rr) * HD + k);
            acc[rr][0] += xv.x * w0.x + xv.y * w1.x + xv.z * w2.x + xv.w * w3.x;
            acc[rr][1] += xv.x * w0.y + xv.y * w1.y + xv.z * w2.y + xv.w * w3.y;
            acc[rr][2] += xv.x * w0.z + xv.y * w1.z + xv.z * w2.z + xv.w * w3.z;
            acc[rr][3] += xv.x * w0.w + xv.y * w1.w + xv.z * w2.w + xv.w * w3.w;
        }
    }
    #pragma unroll
    for (int rr = 0; rr < 4; rr++) {
        const int row = r0 + rb + rr;
        *(float4*)(outp + (size_t)row * HD + c0) =
            make_float4(acc[rr][0], acc[rr][1], acc[rr][2], acc[rr][3]);
    }
}

__global__ void mvecb_kernel(
    const float* __restrict__ ee_b2, const float* __restrict__ msg_w1,
    const float* __restrict__ msg_b1, const float* __restrict__ msg_b2,
    const float* __restrict__ upd_w1, float* __restrict__ mvec,
    float* __restrict__ b2u)
{
    const int m = blockIdx.x;
    const int l = m & 3;
    const int j = threadIdx.x;
    if (j >= HD) return;
    if (m < 4) {
        const float* W = msg_w1 + (size_t)l * 3 * HD2 + 2 * HD2;
        float s = msg_b1[(size_t)l * HD + j];
        for (int i = 0; i < HD; i++) s += ee_b2[i] * W[(size_t)i * HD + j];
        mvec[(size_t)l * HD + j] = s;
    } else {
        const float* W = upd_w1 + (size_t)l * 2 * HD2 + HD2;
        float s = 0.f;
        for (int i = 0; i < HD; i++) s += msg_b2[(size_t)l * HD + i] * W[(size_t)i * HD + j];
        b2u[(size_t)l * HD + j] = s;
    }
}

__global__ __launch_bounds__(256) void wprep_kernel(
    const float* __restrict__ msg_w1, const float* __restrict__ Mw2,
    const float* __restrict__ upd_w1, const float* __restrict__ upd_w2,
    const float* __restrict__ gw1, const float* __restrict__ ne_w2,
    const float* __restrict__ Mw, u16* __restrict__ wt)
{
    __shared__ float tileL[HD * (HD + 1)];
    const int b = blockIdx.x, t = threadIdx.x;
    const int l = b & 3;
    const float* S;
    if (b < 4)       S = msg_w1 + (size_t)l * 3 * HD2;
    else if (b < 8)  S = msg_w1 + (size_t)l * 3 * HD2 + HD2;
    else if (b < 12) S = Mw + (size_t)l * HD2;
    else if (b < 16) S = Mw2 + (size_t)l * HD2;
    else if (b < 20) S = upd_w1 + (size_t)l * 2 * HD2;
    else if (b < 24) S = upd_w1 + (size_t)l * 2 * HD2 + HD2;
    else if (b < 28) S = upd_w2 + (size_t)l * HD2;
    else if (b == 28) S = gw1;
    else             S = ne_w2;
    u16* D = wt + (size_t)b * HD2;
    for (int i = t; i < HD2; i += 256) {
        const int k = i >> 7, n = i & 127;
        tileL[k * (HD + 1) + n] = S[i];
    }
    __syncthreads();
    for (int i = t; i < HD2; i += 256) {
        const int n = i >> 7, k = i & 127;
        D[i] = f2bf(tileL[k * (HD + 1) + n]);
    }
}

// ---------------------------------------------------------------------------
// Node encoder layer 1 (7 -> 128), bf16 out.
// ---------------------------------------------------------------------------
__global__ __launch_bounds__(256) void ne1_kernel(
    const float* __restrict__ nf, const float* __restrict__ w1,
    const float* __restrict__ b1, u16* __restrict__ out)
{
    __shared__ float w1s[7 * HD];
    __shared__ float b1s[HD];
    const int t = threadIdx.x;
    for (int i = t; i < 7 * HD; i += 256) w1s[i] = w1[i];
    if (t < HD) b1s[t] = b1[t];
    __syncthreads();
    const int row = blockIdx.x * 32 + (t >> 3);
    const int c0 = (t & 7) * 16;
    if (row < NN) {
        float f[7];
        #pragma unroll
        for (int k = 0; k < 7; k++) f[k] = nf[(size_t)row * 7 + k];
        float o[16];
        #pragma unroll
        for (int c = 0; c < 16; c++) {
            float a = b1s[c0 + c];
            #pragma unroll
            for (int k = 0; k < 7; k++) a += f[k] * w1s[k * HD + c0 + c];
            o[c] = fmaxf(a, 0.f);
        }
        uint4 v0 = make_uint4(pk2(o[0], o[1]), pk2(o[2], o[3]), pk2(o[4], o[5]), pk2(o[6], o[7]));
        uint4 v1 = make_uint4(pk2(o[8], o[9]), pk2(o[10], o[11]), pk2(o[12], o[13]), pk2(o[14], o[15]));
        *(uint4*)(out + (size_t)row * HD + c0) = v0;
        *(uint4*)(out + (size_t)row * HD + c0 + 8) = v1;
    }
}

// ---------------------------------------------------------------------------
// CSR build.
// ---------------------------------------------------------------------------
__global__ void deg_count_kernel(const int* __restrict__ dst, int* __restrict__ deg) {
    const int i = blockIdx.x * 256 + threadIdx.x;
    if (i < NE) atomicAdd(&deg[dst[i]], 1);
}
__global__ void scan1_kernel(const int* __restrict__ deg, int* __restrict__ part) {
    __shared__ int s[256];
    const int t = threadIdx.x, i = blockIdx.x * 256 + t;
    s[t] = (i < NN) ? deg[i] : 0;
    __syncthreads();
    for (int d = 128; d > 0; d >>= 1) { if (t < d) s[t] += s[t + d]; __syncthreads(); }
    if (t == 0) part[blockIdx.x] = s[0];
}
__global__ void scan2_kernel(int* __restrict__ part, int nb) {
    if (threadIdx.x == 0 && blockIdx.x == 0) {
        int run = 0;
        for (int b = 0; b < nb; b++) { const int v = part[b]; part[b] = run; run += v; }
    }
}
__global__ void scan3_kernel(const int* __restrict__ deg, const int* __restrict__ part,
                             int* __restrict__ off, int* __restrict__ pos,
                             float* __restrict__ degf) {
    __shared__ int s[256];
    const int t = threadIdx.x, i = blockIdx.x * 256 + t;
    const int v = (i < NN) ? deg[i] : 0;
    s[t] = v;
    __syncthreads();
    for (int d = 1; d < 256; d <<= 1) {
        const int x = (t >= d) ? s[t - d] : 0;
        __syncthreads();
        s[t] += x;
        __syncthreads();
    }
    const int excl = s[t] - v + part[blockIdx.x];
    if (i < NN) {
        off[i] = excl; pos[i] = excl;
        degf[i] = (float)v;
        if (i == NN - 1) off[NN] = excl + v;
    }
}
__global__ void scatter_kernel(const int* __restrict__ src, const int* __restrict__ dst,
                               const float* __restrict__ ef, int* __restrict__ pos,
                               float2* __restrict__ sef, int* __restrict__ ssrc,
                               int* __restrict__ sdst) {
    const int e = blockIdx.x * 256 + threadIdx.x;
    if (e < NE) {
        const int d = dst[e];
        const int p = atomicAdd(&pos[d], 1);
        sef[p] = make_float2(ef[2 * e], ef[2 * e + 1]);
        ssrc[p] = src[e]; sdst[p] = d;
    }
}

__global__ void bounds_kernel(const int* __restrict__ gid, int* __restrict__ gs) {
    const int g = threadIdx.x;
    if (g <= NG) {
        int lo = 0, hi = NN;
        while (lo < hi) {
            const int mid = (lo + hi) >> 1;
            if (gid[mid] < g) lo = mid + 1; else hi = mid;
        }
        gs[g] = lo;
    }
}

// ---------------------------------------------------------------------------
// Pooling (3-stage) + policy head (measured good).
// ---------------------------------------------------------------------------
__global__ __launch_bounds__(256) void poolA_kernel(
    const float* __restrict__ gate, const int* __restrict__ gs,
    float* __restrict__ ex, float* __restrict__ gz)
{
    __shared__ float red[256];
    const int g = blockIdx.x, t = threadIdx.x;
    const int s = gs[g], e = gs[g + 1];
    if (s >= e) {
        if (t == 0) gz[g] = 1.f;
        return;
    }
    float m = -3.4e38f;
    for (int i = s + t; i < e; i += 256) m = fmaxf(m, gate[i]);
    red[t] = m; __syncthreads();
    for (int d = 128; d > 0; d >>= 1) {
        if (t < d) red[t] = fmaxf(red[t], red[t + d]);
        __syncthreads();
    }
    const float gm = red[0];
    __syncthreads();
    float zs = 0.f;
    for (int i = s + t; i < e; i += 256) {
        const float ev = expf(gate[i] - gm);
        ex[i] = ev; zs += ev;
    }
    red[t] = zs; __syncthreads();
    for (int d = 128; d > 0; d >>= 1) {
        if (t < d) red[t] += red[t + d];
        __syncthreads();
    }
    if (t == 0) gz[g] = red[0];
}

__global__ __launch_bounds__(256) void poolB_kernel(
    const float* __restrict__ ex, const int* __restrict__ gs,
    const u16* __restrict__ hb, float* __restrict__ partial)
{
    __shared__ float redL[16][132];
    const int b = blockIdx.x;
    const int g = b / PSLICE, sl = b % PSLICE;
    const int lo = gs[g], hi = gs[g + 1];
    const int len = hi - lo;
    const int chunk = (len + PSLICE - 1) / PSLICE;
    const int ns = lo + sl * chunk;
    const int ne = min(ns + chunk, hi);
    const int t = threadIdx.x;
    const int c8 = (t & 15) * 8;
    const int ro = t >> 4;
    float acc[8] = {0.f, 0.f, 0.f, 0.f, 0.f, 0.f, 0.f, 0.f};
    for (int n = ns + ro; n < ne; n += 16) {
        const float w = ex[n];
        const ushort4 h0 = *(const ushort4*)(hb + (size_t)n * HD + c8);
        const ushort4 h1 = *(const ushort4*)(hb + (size_t)n * HD + c8 + 4);
        acc[0] += w * bf2f(h0.x); acc[1] += w * bf2f(h0.y);
        acc[2] += w * bf2f(h0.z); acc[3] += w * bf2f(h0.w);
        acc[4] += w * bf2f(h1.x); acc[5] += w * bf2f(h1.y);
        acc[6] += w * bf2f(h1.z); acc[7] += w * bf2f(h1.w);
    }
    #pragma unroll
    for (int j = 0; j < 8; j++) redL[ro][c8 + j] = acc[j];
    __syncthreads();
    if (t < HD) {
        float s = 0.f;
        #pragma unroll
        for (int r = 0; r < 16; r++) s += redL[r][t];
        partial[(size_t)b * HD + t] = s;
    }
}

__global__ void poolC_kernel(const float* __restrict__ partial,
                             const float* __restrict__ gz,
                             float* __restrict__ emb)
{
    const int g = blockIdx.x, t = threadIdx.x;
    float s = 0.f;
    #pragma unroll
    for (int sl = 0; sl < PSLICE; sl++)
        s += partial[(size_t)(g * PSLICE + sl) * HD + t];
    emb[(size_t)g * HD + t] = s / gz[g];
}

__global__ __launch_bounds__(256) void policy_kernel(
    const float* __restrict__ emb,
    const float* __restrict__ w1, const float* __restrict__ b1,
    const float* __restrict__ w2, const float* __restrict__ b2,
    const float* __restrict__ w3, const float* __restrict__ b3,
    float* __restrict__ out)
{
    __shared__ float A[NG * HD];
    __shared__ float Bs[NG * HD];
    const int t = threadIdx.x;
    for (int i = t; i < NG * HD / 4; i += 256)
        ((float4*)A)[i] = ((const float4*)emb)[i];
    __syncthreads();
    const int c0 = (t & 31) * 4;
    const int rb = (t >> 5) * 8;
    {
        float4 bv = *(const float4*)(b1 + c0);
        for (int rr = 0; rr < 8; rr++) {
            const int r = rb + rr;
            float a0 = bv.x, a1 = bv.y, a2 = bv.z, a3 = bv.w;
            for (int k = 0; k < HD; k++) {
                const float x = A[r * HD + k];
                float4 wv = *(const float4*)(w1 + k * HD + c0);
                a0 += x * wv.x; a1 += x * wv.y; a2 += x * wv.z; a3 += x * wv.w;
            }
            *(float4*)(Bs + r * HD + c0) =
                make_float4(fmaxf(a0, 0.f), fmaxf(a1, 0.f), fmaxf(a2, 0.f), fmaxf(a3, 0.f));
        }
    }
    __syncthreads();
    {
        float4 bv = *(const float4*)(b2 + c0);
        for (int rr = 0; rr < 8; rr++) {
            const int r = rb + rr;
            float a0 = bv.x, a1 = bv.y, a2 = bv.z, a3 = bv.w;
            for (int k = 0; k < HD; k++) {
                const float x = Bs[r * HD + k];
                float4 wv = *(const float4*)(w2 + k * HD + c0);
                a0 += x * wv.x; a1 += x * wv.y; a2 += x * wv.z; a3 += x * wv.w;
            }
            *(float4*)(A + r * HD + c0) =
                make_float4(fmaxf(a0, 0.f), fmaxf(a1, 0.f), fmaxf(a2, 0.f), fmaxf(a3, 0.f));
        }
    }
    __syncthreads();
    {
        float4 bv = *(const float4*)(b3 + c0);
        for (int rr = 0; rr < 8; rr++) {
            const int r = rb + rr;
            float a[4] = {bv.x, bv.y, bv.z, bv.w};
            for (int k = 0; k < HD; k++) {
                const float x = A[r * HD + k];
                float4 wv = *(const float4*)(w3 + k * HD + c0);
                a[0] += x * wv.x; a[1] += x * wv.y; a[2] += x * wv.z; a[3] += x * wv.w;
            }
            #pragma unroll
            for (int j = 0; j < 4; j++) {
                const int c = c0 + j;
                if (c < 64) {
                    out[r * 64 + c] = a[j];
                } else {
                    const float ls = fminf(fmaxf(a[j], -20.f), 2.f);
                    out[4096 + r * 64 + (c - 64)] = expf(ls);
                }
            }
        }
    }
}

// ---------------------------------------------------------------------------
extern "C" void kernel_launch(void* const* d_in, const int* in_sizes, int n_in,
                              void* d_out, int out_size, void* d_ws, size_t ws_size,
                              hipStream_t stream) {
    const float* node_feat = (const float*)d_in[0];
    const float* edge_feat = (const float*)d_in[1];
    const float* ne_w1 = (const float*)d_in[2];
    const float* ne_b1 = (const float*)d_in[3];
    const float* ne_w2 = (const float*)d_in[4];
    const float* ne_b2 = (const float*)d_in[5];
    const float* ee_w1 = (const float*)d_in[6];
    const float* ee_b1 = (const float*)d_in[7];
    const float* ee_w2 = (const float*)d_in[8];
    const float* ee_b2 = (const float*)d_in[9];
    const float* msg_w1 = (const float*)d_in[10];
    const float* msg_b1 = (const float*)d_in[11];
    const float* msg_w2 = (const float*)d_in[12];
    const float* msg_b2 = (const float*)d_in[13];
    const float* upd_w1 = (const float*)d_in[14];
    const float* upd_b1 = (const float*)d_in[15];
    const float* upd_w2 = (const float*)d_in[16];
    const float* upd_b2 = (const float*)d_in[17];
    const float* gate_w1 = (const float*)d_in[18];
    const float* gate_b1 = (const float*)d_in[19];
    const float* gate_w2 = (const float*)d_in[20];
    const float* gate_b2 = (const float*)d_in[21];
    const float* pol_w1 = (const float*)d_in[22];
    const float* pol_b1 = (const float*)d_in[23];
    const float* pol_w2 = (const float*)d_in[24];
    const float* pol_b2 = (const float*)d_in[25];
    const float* pol_w3 = (const float*)d_in[26];
    const float* pol_b3 = (const float*)d_in[27];
    const int* src = (const int*)d_in[28];
    const int* dst = (const int*)d_in[29];
    const int* gid = (const int*)d_in[30];

    // ---- workspace layout (~143 MB) ----
    char* p = (char*)d_ws;
    u16* hb   = (u16*)p;    p += (size_t)NN * HD * 2;
    u16* Pb   = (u16*)p;    p += (size_t)NN * HD * 2;
    u16* Qb   = (u16*)p;    p += (size_t)NN * HD * 2;
    u16* aggb = (u16*)p;    p += (size_t)NN * HD * 2;
    u16* tub  = (u16*)p;    p += (size_t)NN * HD * 2;
    float2* sef = (float2*)p; p += (size_t)NE * 8;
    int* ssrc = (int*)p;    p += (size_t)NE * 4;
    int* sdst = (int*)p;    p += (size_t)NE * 4;
    int* off  = (int*)p;    p += (size_t)(NN + 4) * 4;
    int* pos  = (int*)p;    p += (size_t)NN * 4;
    int* deg  = (int*)p;    p += (size_t)NN * 4;
    float* degf = (float*)p; p += (size_t)NN * 4;
    float* gate = (float*)p; p += (size_t)NN * 4;
    float* ex   = (float*)p; p += (size_t)NN * 4;
    int* part = (int*)p;    p += 2048;
    int* gs   = (int*)p;    p += 512;
    float* gz   = (float*)p; p += 256;
    float* emb = (float*)p; p += (size_t)NG * HD * 4;
    float* partialP = (float*)p; p += (size_t)NG * PSLICE * HD * 4;
    float* Mw  = (float*)p; p += (size_t)NLAYER * HD2 * 4;
    float* Mw2 = (float*)p; p += (size_t)NLAYER * HD2 * 4;
    float* mvec = (float*)p; p += (size_t)NLAYER * HD * 4;
    float* b2u  = (float*)p; p += (size_t)NLAYER * HD * 4;
    u16* wt = (u16*)p;      p += (size_t)30 * HD2 * 2;

    // ---- CSR build ----
    hipMemsetAsync(deg, 0, (size_t)NN * 4, stream);
    deg_count_kernel<<<(NE + 255) / 256, 256, 0, stream>>>(dst, deg);
    scan1_kernel<<<SCAN_NB, 256, 0, stream>>>(deg, part);
    scan2_kernel<<<1, 64, 0, stream>>>(part, SCAN_NB);
    scan3_kernel<<<SCAN_NB, 256, 0, stream>>>(deg, part, off, pos, degf);
    scatter_kernel<<<(NE + 255) / 256, 256, 0, stream>>>(src, dst, edge_feat, pos, sef, ssrc, sdst);
    bounds_kernel<<<1, 128, 0, stream>>>(gid, gs);

    // ---- weight folds (batched) + prep ----
    foldgemm_kernel<<<32, 256, 0, stream>>>(ee_w2, msg_w1, msg_w2, upd_w1, Mw, Mw2);
    mvecb_kernel<<<8, 128, 0, stream>>>(ee_b2, msg_w1, msg_b1, msg_b2, upd_w1, mvec, b2u);
    wprep_kernel<<<30, 256, 0, stream>>>(msg_w1, Mw2, upd_w1, upd_w2, gate_w1, ne_w2, Mw, wt);

    // ---- node encoder ----
    ne1_kernel<<<3125, 256, 0, stream>>>(node_feat, ne_w1, ne_b1, Pb);
    mgemm_kernel<false, false><<<512, 256, 0, stream>>>(
        Pb, wt + (size_t)29 * HD2, ne_b2, nullptr, nullptr, hb, NN, nullptr, nullptr, nullptr);

    // ---- message-passing layers (4 dispatches/layer) ----
    for (int l = 0; l < NLAYER; l++) {
        pqtgemm_kernel<<<512, 256, 0, stream>>>(
            hb, wt + (size_t)(0 + l) * HD2, wt + (size_t)(4 + l) * HD2,
            wt + (size_t)(16 + l) * HD2, upd_b1 + (size_t)l * HD, Pb, Qb, tub, NN);
        edge_mfma_kernel<<<NN / 32, 256, 0, stream>>>(sef, ssrc, sdst, off, ee_w1, ee_b1,
            wt + (size_t)(8 + l) * HD2, mvec + (size_t)l * HD, Pb, Qb, aggb);
        mgemm_kernel<true, false><<<512, 256, 0, stream>>>(
            aggb, wt + (size_t)(12 + l) * HD2, b2u + (size_t)l * HD, degf, tub, Pb, NN,
            nullptr, nullptr, nullptr);
        mgemm_kernel<false, false><<<512, 256, 0, stream>>>(
            Pb, wt + (size_t)(24 + l) * HD2, upd_b2 + (size_t)l * HD, nullptr, hb, hb, NN,
            nullptr, nullptr, nullptr);
    }

    // ---- gate (fused dot) + pooling (3-stage) + policy ----
    mgemm_kernel<true, true><<<512, 256, 0, stream>>>(
        hb, wt + (size_t)28 * HD2, gate_b1, nullptr, nullptr, nullptr, NN,
        gate_w2, gate_b2, gate);
    poolA_kernel<<<NG, 256, 0, stream>>>(gate, gs, ex, gz);
    poolB_kernel<<<NG * PSLICE, 256, 0, stream>>>(ex, gs, hb, partialP);
    poolC_kernel<<<NG, 128, 0, stream>>>(partialP, gz, emb);
    policy_kernel<<<1, 256, 0, stream>>>(emb, pol_w1, pol_b1, pol_w2, pol_b2, pol_w3, pol_b3, (float*)d_out);
}